// Round 4
// baseline (1543.723 us; speedup 1.0000x reference)
//
#include <hip/hip_runtime.h>

#define B_ 8
#define V_ 2048
#define D_ 3
#define M_ (B_*V_)   // 16384 rows
#define NBLK 512

typedef __attribute__((ext_vector_type(8))) short short8;
typedef __attribute__((ext_vector_type(4))) float f32x4;

__device__ inline void async_copy16(const void* g, void* lds) {
  __builtin_amdgcn_global_load_lds(
      (const __attribute__((address_space(1))) unsigned int*)g,
      (__attribute__((address_space(3))) unsigned int*)lds, 16, 0, 0);
}

__device__ inline void split_bf16(float v, short& hi, short& lo) {
  unsigned u  = __float_as_uint(v);
  unsigned hb = u & 0xFFFF0000u;
  float d = v - __uint_as_float(hb);
  hi = (short)(hb >> 16);
  lo = (short)(__float_as_uint(d) >> 16);
}

// ---------------------------------------------------------------------------
// Hand-rolled grid barrier (sense-reversing, agent-scope acq/rel atomics).
// Requires all NBLK blocks co-resident: guaranteed by __launch_bounds__(256,2)
// (VGPR<=256 -> 2 blk/CU) x 256 CU = 512 slots = grid size.  Agent-scope
// release/acquire emit the L2 writeback/invalidate ops needed across the
// non-coherent per-XCD L2s (same mechanism as __ockl_grid_sync).
// ---------------------------------------------------------------------------
__device__ inline void grid_sync(unsigned* bar) {
  __syncthreads();
  if (threadIdx.x == 0) {
    unsigned* cnt = bar;
    unsigned* gen = bar + 1;
    unsigned g = __hip_atomic_load(gen, __ATOMIC_RELAXED, __HIP_MEMORY_SCOPE_AGENT);
    unsigned a = __hip_atomic_fetch_add(cnt, 1u, __ATOMIC_ACQ_REL, __HIP_MEMORY_SCOPE_AGENT);
    if (a == NBLK - 1) {   // last to arrive: reset + release
      __hip_atomic_store(cnt, 0u, __ATOMIC_RELAXED, __HIP_MEMORY_SCOPE_AGENT);
      __hip_atomic_fetch_add(gen, 1u, __ATOMIC_ACQ_REL, __HIP_MEMORY_SCOPE_AGENT);
    } else {
      while (__hip_atomic_load(gen, __ATOMIC_ACQUIRE, __HIP_MEMORY_SCOPE_AGENT) == g)
        __builtin_amdgcn_s_sleep(2);
    }
  }
  __syncthreads();
}

__global__ void k_init(unsigned* bar) { bar[0] = 0u; bar[1] = 0u; }

struct Params {
  const float *x, *L, *w1, *b1, *w2, *b2, *fw1, *fb1, *fw2, *fb2;
  float *out;
  float *xa, *xb, *xc, *y1, *zb, *zc;
  short *ZKh, *ZKl, *y2h, *y2l, *h1h, *h1l;
  short *ZtAh, *ZtAl, *ZtBh, *ZtBl;
  short *w1h, *w1l, *w2h, *w2l, *fw1h, *fw1l, *fw2h, *fw2l;
  short *XKh, *XKl;
  unsigned *bar;
};

// LDS union: max(24 KB cheby1, 48 KB cheby2, 32 KB gemm) = 48 KB
union SMem {
  float sx[3][V_];                                         // cheby1: 24 KB
  struct { float a[2][32*64]; short bh[2][64*64]; short bl[2][64*64]; } c2;  // 48 KB
  struct { short ah[64*64]; short al[64*64]; short wh[64*64]; short wl[64*64]; } g; // 32 KB
};

// ---------------------------------------------------------------------------
// prep phase: XK slot0 (+zero pads) + xa transpose + all weight splits.
// 512 blocks x 256 threads, 10 grid-stride iters over 1,290,240 elements.
// ---------------------------------------------------------------------------
__device__ void prep_phase(const Params& p) {
  for (int c = 0; c < 10; c++) {
    int i = c*131072 + blockIdx.x*256 + threadIdx.x;
    short hi, lo;
    if (i < M_*64) {   // XK: row r = i>>6, slot s = i&63; slot = f*6+k, k=0 live
      int r = i >> 6, s = i & 63;
      float val = 0.f;
      if (s == 0 || s == 6 || s == 12) {
        int f = s / 6;
        int b = r >> 11, v = r & (V_-1);
        val = p.x[((size_t)b*D_ + f)*V_ + v];
        p.xa[(size_t)r*3 + f] = val;
      }
      split_bf16(val, hi, lo);
      p.XKh[i] = hi; p.XKl[i] = lo;
    } else {
      int j = i - M_*64;
      if (j < 4096) {          // w1: [64,18] -> [64,64] padded
        int k = j & 63;
        float v = (k < 18) ? p.w1[(j>>6)*18 + k] : 0.f;
        split_bf16(v, hi, lo); p.w1h[j] = hi; p.w1l[j] = lo;
      } else if ((j -= 4096) < 40960) {
        split_bf16(p.w2[j],  hi, lo); p.w2h[j]=hi;  p.w2l[j]=lo;
      } else if ((j -= 40960) < 65536) {
        split_bf16(p.fw1[j], hi, lo); p.fw1h[j]=hi; p.fw1l[j]=lo;
      } else if ((j -= 65536) < 131072) {
        split_bf16(p.fw2[j], hi, lo); p.fw2h[j]=hi; p.fw2l[j]=lo;
      }
    }
  }
}

// ---------------------------------------------------------------------------
// cheby1 phase: xn = alpha*(L@xc) - beta*xp.  512 blocks: 32 rows/block,
// 8 rows/wave, batch pinned (b = bid&7).  Per-row accumulation tree is
// identical to the round-2 verified kernel -> bit-identical results.
// ---------------------------------------------------------------------------
__device__ void cheby1_phase(const Params& p, SMem& sm,
    const float* xc, const float* xp, float* xn,
    float alpha, float beta, int kidx) {
  int b  = blockIdx.x & 7;
  int r0 = (blockIdx.x >> 3) * 32;   // 64 row-tiles of 32
  const float* xcb = xc + (size_t)b*V_*D_;
  for (int i = threadIdx.x; i < V_*D_; i += 256) {
    int u = i / 3, f = i - u*3;
    sm.sx[f][u] = xcb[i];
  }
  __syncthreads();
  int w = threadIdx.x >> 6, lane = threadIdx.x & 63;
  const float4* X0 = (const float4*)sm.sx[0];
  const float4* X1 = (const float4*)sm.sx[1];
  const float4* X2 = (const float4*)sm.sx[2];
  int rbase = r0 + w*8;
  const float4* Lr = (const float4*)(p.L + ((size_t)b*V_ + rbase)*V_);

  float acc[8][3];
  #pragma unroll
  for (int rr = 0; rr < 8; rr++) { acc[rr][0]=0.f; acc[rr][1]=0.f; acc[rr][2]=0.f; }

  #pragma unroll 2
  for (int it = 0; it < 8; it++) {
    int u4 = it*64 + lane;
    float4 x0 = X0[u4], x1 = X1[u4], x2 = X2[u4];
    #pragma unroll
    for (int rr = 0; rr < 8; rr++) {
      float4 lv = Lr[(size_t)rr*512 + u4];
      acc[rr][0] = fmaf(lv.x,x0.x,fmaf(lv.y,x0.y,fmaf(lv.z,x0.z,fmaf(lv.w,x0.w,acc[rr][0]))));
      acc[rr][1] = fmaf(lv.x,x1.x,fmaf(lv.y,x1.y,fmaf(lv.z,x1.z,fmaf(lv.w,x1.w,acc[rr][1]))));
      acc[rr][2] = fmaf(lv.x,x2.x,fmaf(lv.y,x2.y,fmaf(lv.z,x2.z,fmaf(lv.w,x2.w,acc[rr][2]))));
    }
  }
  #pragma unroll
  for (int off = 32; off > 0; off >>= 1)
    #pragma unroll
    for (int rr = 0; rr < 8; rr++)
      #pragma unroll
      for (int f = 0; f < 3; f++)
        acc[rr][f] += __shfl_down(acc[rr][f], off);

  if (lane == 0) {
    size_t base = ((size_t)b*V_ + rbase)*3;   // 24 consecutive floats
    float v[24];
    #pragma unroll
    for (int rr = 0; rr < 8; rr++)
      #pragma unroll
      for (int f = 0; f < 3; f++)
        v[rr*3+f] = alpha*acc[rr][f];
    if (beta != 0.f) {
      const float4* xp4 = (const float4*)(xp + base);
      #pragma unroll
      for (int q = 0; q < 6; q++) {
        float4 pv = xp4[q];
        v[q*4+0] -= beta*pv.x; v[q*4+1] -= beta*pv.y;
        v[q*4+2] -= beta*pv.z; v[q*4+3] -= beta*pv.w;
      }
    }
    float4* xn4 = (float4*)(xn + base);
    #pragma unroll
    for (int q = 0; q < 6; q++)
      xn4[q] = make_float4(v[q*4], v[q*4+1], v[q*4+2], v[q*4+3]);
    #pragma unroll
    for (int rr = 0; rr < 8; rr++)
      #pragma unroll
      for (int f = 0; f < 3; f++) {
        short hi, lo; split_bf16(v[rr*3+f], hi, lo);
        size_t o = ((size_t)b*V_ + rbase + rr)*64 + f*6 + kidx;
        p.XKh[o] = hi; p.XKl[o] = lo;
      }
  }
}

// ---------------------------------------------------------------------------
// cheby2 phase: Zn = alpha*(L @ z) - beta*Zp ; split-bf16 MFMA.
// 32-row x 64-col tiles, 512 blocks, double-buffered (verbatim from the
// round-2 verified kernel, LDS moved into the union).
// ---------------------------------------------------------------------------
__device__ void cheby2_phase(const Params& p, SMem& sm,
    const short* Zth, const short* Ztl, const float* Zp,
    float* Zn, short* Znth, short* Zntl,
    float alpha, float beta, int kidx) {
  int b  = blockIdx.x & 7;              // batch -> XCD pin
  int r0 = (blockIdx.x >> 3) * 32;      // 64 row-tiles
  const float* Lb   = p.L + (size_t)b*V_*V_;
  const short* Zthb = Zth + (size_t)b*64*V_;
  const short* Ztlb = Ztl + (size_t)b*64*V_;

  int tid  = threadIdx.x;
  int w    = tid >> 6;
  int lane = tid & 63;
  int lm   = lane & 15;
  int quad = lane >> 4;
  int cbase = w * 16;

  int f1  = tid + 256;
  int rA0 = tid >> 4, cA0 = (tid & 15) ^ (rA0 & 15);
  int rA1 = f1 >> 4,  cA1 = (f1 & 15) ^ (rA1 & 15);
  size_t gA0 = (size_t)(r0 + rA0)*V_ + cA0*4;
  size_t gA1 = (size_t)(r0 + rA1)*V_ + cA1*4;
  int nB0 = tid >> 3, cB0 = (tid & 7) ^ (nB0 & 7);
  int nB1 = f1 >> 3,  cB1 = (f1 & 7) ^ (nB1 & 7);
  size_t gB0 = (size_t)nB0*V_ + cB0*8;
  size_t gB1 = (size_t)nB1*V_ + cB1*8;

  auto stage = [&](int bb, int k0) {
    async_copy16(Lb   + gA0 + k0, &sm.c2.a[bb][tid*4]);
    async_copy16(Lb   + gA1 + k0, &sm.c2.a[bb][f1*4]);
    async_copy16(Zthb + gB0 + k0, &sm.c2.bh[bb][tid*8]);
    async_copy16(Ztlb + gB0 + k0, &sm.c2.bl[bb][tid*8]);
    async_copy16(Zthb + gB1 + k0, &sm.c2.bh[bb][f1*8]);
    async_copy16(Ztlb + gB1 + k0, &sm.c2.bl[bb][f1*8]);
  };

  f32x4 acc[2] = {{0.f,0.f,0.f,0.f},{0.f,0.f,0.f,0.f}};

  stage(0, 0);

  for (int s = 0; s < V_/64; s++) {
    int bb = s & 1;
    asm volatile("s_waitcnt vmcnt(0)" ::: "memory");
    __builtin_amdgcn_s_barrier();
    __builtin_amdgcn_sched_barrier(0);
    if (s < V_/64 - 1) stage(bb ^ 1, (s+1)*64);

    const f32x4*  sAv  = (const f32x4*)sm.c2.a[bb];
    const short8* sBhv = (const short8*)sm.c2.bh[bb];
    const short8* sBlv = (const short8*)sm.c2.bl[bb];

    #pragma unroll
    for (int ks = 0; ks < 2; ks++) {
      int koff = ks * 32;
      short8 ah[2], al[2];
      #pragma unroll
      for (int t = 0; t < 2; t++) {
        int r = t*16 + lm;
        int ca = (koff >> 2) + 2*quad;
        f32x4 a0 = sAv[r*16 + (ca ^ (r & 15))];
        f32x4 a1 = sAv[r*16 + ((ca + 1) ^ (r & 15))];
        float av[8] = {a0.x, a0.y, a0.z, a0.w, a1.x, a1.y, a1.z, a1.w};
        #pragma unroll
        for (int j = 0; j < 8; j++) {
          short hi, lo; split_bf16(av[j], hi, lo);
          ah[t][j] = hi; al[t][j] = lo;
        }
      }
      int cb = (koff >> 3) + quad;
      int n = cbase + lm;
      short8 bh = sBhv[n*8 + (cb ^ (n & 7))];
      short8 bl = sBlv[n*8 + (cb ^ (n & 7))];
      __builtin_amdgcn_s_setprio(1);
      #pragma unroll
      for (int t = 0; t < 2; t++) {
        acc[t] = __builtin_amdgcn_mfma_f32_16x16x32_bf16(ah[t], bh, acc[t], 0, 0, 0);
        acc[t] = __builtin_amdgcn_mfma_f32_16x16x32_bf16(ah[t], bl, acc[t], 0, 0, 0);
        acc[t] = __builtin_amdgcn_mfma_f32_16x16x32_bf16(al[t], bh, acc[t], 0, 0, 0);
      }
      __builtin_amdgcn_s_setprio(0);
    }
  }

  int n = cbase + lm;
  #pragma unroll
  for (int t = 0; t < 2; t++) {
    #pragma unroll
    for (int i = 0; i < 4; i++) {
      int r = r0 + t*16 + quad*4 + i;
      size_t rowb = (size_t)b*V_ + r;
      float v = alpha * acc[t][i];
      if (beta != 0.f) v -= beta * Zp[rowb*64 + n];
      Zn[rowb*64 + n] = v;
      short hi, lo; split_bf16(v, hi, lo);
      size_t ok = rowb*320 + (size_t)n*5 + kidx;
      p.ZKh[ok] = hi; p.ZKl[ok] = lo;
      size_t o = ((size_t)b*64 + n)*V_ + r;
      Znth[o] = hi; Zntl[o] = lo;
    }
  }
}

// ---------------------------------------------------------------------------
// gemm_tile: one 64x64 output tile of C = relu(A[M,K] @ W[N,K]^T + bias).
// Entry __syncthreads guards LDS reuse across consecutive tiles/phases.
// ---------------------------------------------------------------------------
__device__ __forceinline__ void gemm_tile(
    const short* __restrict__ Ah, const short* __restrict__ Al,
    const short* __restrict__ Wh, const short* __restrict__ Wl,
    const float* __restrict__ bias, int N, int K, int row0, int col0,
    short* sAh, short* sAl, short* sWh, short* sWl,
    float* __restrict__ Cf, short* __restrict__ Ch, short* __restrict__ Cl,
    short* __restrict__ Ph, short* __restrict__ Pl, int packMul, int packStride,
    short* __restrict__ Th, short* __restrict__ Tl) {
  int tid = threadIdx.x, w = tid >> 6, lane = tid & 63;
  int lm = lane & 15, quad = lane >> 4;
  int wm = (w & 1) * 32, wn = (w >> 1) * 32;

  __syncthreads();   // previous phase/tile may still be reading this LDS

  const short8* vAh = (const short8*)sAh;
  const short8* vAl = (const short8*)sAl;
  const short8* vWh = (const short8*)sWh;
  const short8* vWl = (const short8*)sWl;

  f32x4 acc[2][2] = {{{0.f,0.f,0.f,0.f},{0.f,0.f,0.f,0.f}},
                     {{0.f,0.f,0.f,0.f},{0.f,0.f,0.f,0.f}}};

  for (int k0 = 0; k0 < K; k0 += 64) {
    if (k0) __syncthreads();
    #pragma unroll
    for (int t = 0; t < 2; t++) {
      int f = t*256 + tid;
      int r = f >> 3, pp = f & 7;
      int c = pp ^ (r & 7);
      size_t goA = (size_t)(row0 + r)*K + k0 + c*8;
      size_t goW = (size_t)(col0 + r)*K + k0 + c*8;
      async_copy16(Ah + goA, &sAh[f*8]);
      async_copy16(Al + goA, &sAl[f*8]);
      async_copy16(Wh + goW, &sWh[f*8]);
      async_copy16(Wl + goW, &sWl[f*8]);
    }
    __syncthreads();

    #pragma unroll
    for (int ks = 0; ks < 2; ks++) {
      int kc = ks*4 + quad;
      short8 a_h[2], a_l[2], b_h[2], b_l[2];
      #pragma unroll
      for (int i = 0; i < 2; i++) {
        int m = wm + i*16 + lm;
        a_h[i] = vAh[m*8 + (kc ^ (m & 7))];
        a_l[i] = vAl[m*8 + (kc ^ (m & 7))];
      }
      #pragma unroll
      for (int j = 0; j < 2; j++) {
        int n = wn + j*16 + lm;
        b_h[j] = vWh[n*8 + (kc ^ (n & 7))];
        b_l[j] = vWl[n*8 + (kc ^ (n & 7))];
      }
      #pragma unroll
      for (int i = 0; i < 2; i++)
        #pragma unroll
        for (int j = 0; j < 2; j++) {
          acc[i][j] = __builtin_amdgcn_mfma_f32_16x16x32_bf16(a_h[i], b_h[j], acc[i][j], 0, 0, 0);
          acc[i][j] = __builtin_amdgcn_mfma_f32_16x16x32_bf16(a_h[i], b_l[j], acc[i][j], 0, 0, 0);
          acc[i][j] = __builtin_amdgcn_mfma_f32_16x16x32_bf16(a_l[i], b_h[j], acc[i][j], 0, 0, 0);
        }
    }
  }

  #pragma unroll
  for (int i = 0; i < 2; i++)
    #pragma unroll
    for (int j = 0; j < 2; j++) {
      int col = col0 + wn + j*16 + lm;
      float bj = bias[col];
      #pragma unroll
      for (int g = 0; g < 4; g++) {
        int row = row0 + wm + i*16 + quad*4 + g;
        float v = acc[i][j][g] + bj;
        v = v > 0.f ? v : 0.f;
        if (Cf) Cf[(size_t)row*N + col] = v;
        short hi, lo;
        if (Ch || Ph || Th) split_bf16(v, hi, lo);
        if (Ch) {
          Ch[(size_t)row*N + col] = hi;
          Cl[(size_t)row*N + col] = lo;
        }
        if (Ph) {
          size_t o = (size_t)row*packStride + (size_t)col*packMul;
          Ph[o] = hi; Pl[o] = lo;
        }
        if (Th) {  // transposed [B,64,V] (N==64)
          int bb = row >> 11, vv = row & (V_-1);
          size_t o = ((size_t)bb*64 + col)*V_ + vv;
          Th[o] = hi; Tl[o] = lo;
        }
      }
    }
}

// ---------------------------------------------------------------------------
// The whole network in ONE kernel: 512 blocks x 256 threads (all resident),
// 13 phases separated by the hand-rolled grid barrier.
// ---------------------------------------------------------------------------
__global__ __launch_bounds__(256, 2) void k_mega(Params p) {
  __shared__ SMem sm;

  // P0: prep
  prep_phase(p);
  grid_sync(p.bar);

  // P1..P5: cheby1 chain  (xa -> xb -> xc -> xa -> xb -> xc)
  cheby1_phase(p, sm, p.xa, p.xa, p.xb, 1.f, 0.f, 1); grid_sync(p.bar);
  cheby1_phase(p, sm, p.xb, p.xa, p.xc, 2.f, 1.f, 2); grid_sync(p.bar);
  cheby1_phase(p, sm, p.xc, p.xb, p.xa, 2.f, 1.f, 3); grid_sync(p.bar);
  cheby1_phase(p, sm, p.xa, p.xc, p.xb, 2.f, 1.f, 4); grid_sync(p.bar);
  cheby1_phase(p, sm, p.xb, p.xa, p.xc, 2.f, 1.f, 5); grid_sync(p.bar);

  // P6: y1 = relu(XK @ w1^T + b1)  (+ ZK slot0 pack + ZtA transposed split)
  if (blockIdx.x < 256)
    gemm_tile(p.XKh, p.XKl, p.w1h, p.w1l, p.b1, 64, 64, blockIdx.x*64, 0,
              sm.g.ah, sm.g.al, sm.g.wh, sm.g.wl,
              p.y1, nullptr, nullptr, p.ZKh, p.ZKl, 5, 320, p.ZtAh, p.ZtAl);
  grid_sync(p.bar);

  // P7..P10: cheby2 chain
  cheby2_phase(p, sm, p.ZtAh, p.ZtAl, p.y1, p.zb, p.ZtBh, p.ZtBl, 1.f, 0.f, 1); grid_sync(p.bar);
  cheby2_phase(p, sm, p.ZtBh, p.ZtBl, p.y1, p.zc, p.ZtAh, p.ZtAl, 2.f, 1.f, 2); grid_sync(p.bar);
  cheby2_phase(p, sm, p.ZtAh, p.ZtAl, p.zb, p.y1, p.ZtBh, p.ZtBl, 2.f, 1.f, 3); grid_sync(p.bar);
  cheby2_phase(p, sm, p.ZtBh, p.ZtBl, p.zc, p.zb, p.ZtAh, p.ZtAl, 2.f, 1.f, 4); grid_sync(p.bar);

  // P11: y2 = relu(ZK @ w2^T + b2)   512 tiles (256 x 2)
  {
    int bm = blockIdx.x & 255, bn = blockIdx.x >> 8;
    gemm_tile(p.ZKh, p.ZKl, p.w2h, p.w2l, p.b2, 128, 320, bm*64, bn*64,
              sm.g.ah, sm.g.al, sm.g.wh, sm.g.wl,
              nullptr, p.y2h, p.y2l, nullptr, nullptr, 0, 0, nullptr, nullptr);
  }
  grid_sync(p.bar);

  // P12: h1 = relu(y2 @ fw1^T + fb1)   2048 tiles -> 4 per block
  for (int t = 0; t < 4; t++) {
    int id = blockIdx.x + t*512;
    int bm = id & 255, bn = id >> 8;
    gemm_tile(p.y2h, p.y2l, p.fw1h, p.fw1l, p.fb1, 512, 128, bm*64, bn*64,
              sm.g.ah, sm.g.al, sm.g.wh, sm.g.wl,
              nullptr, p.h1h, p.h1l, nullptr, nullptr, 0, 0, nullptr, nullptr);
  }
  grid_sync(p.bar);

  // P13: out = relu(h1 @ fw2^T + fb2)  1024 tiles -> 2 per block
  for (int t = 0; t < 2; t++) {
    int id = blockIdx.x + t*512;
    int bm = id & 255, bn = id >> 8;
    gemm_tile(p.h1h, p.h1l, p.fw2h, p.fw2l, p.fb2, 256, 512, bm*64, bn*64,
              sm.g.ah, sm.g.al, sm.g.wh, sm.g.wl,
              p.out, nullptr, nullptr, nullptr, nullptr, 0, 0, nullptr, nullptr);
  }
}

// ---------------------------------------------------------------------------
extern "C" void kernel_launch(void* const* d_in, const int* in_sizes, int n_in,
                              void* d_out, int out_size, void* d_ws, size_t ws_size,
                              hipStream_t stream) {
  Params pp;
  pp.x   = (const float*)d_in[0];
  pp.L   = (const float*)d_in[1];
  pp.w1  = (const float*)d_in[2];
  pp.b1  = (const float*)d_in[3];
  pp.w2  = (const float*)d_in[4];
  pp.b2  = (const float*)d_in[5];
  pp.fw1 = (const float*)d_in[6];
  pp.fb1 = (const float*)d_in[7];
  pp.fw2 = (const float*)d_in[8];
  pp.fb2 = (const float*)d_in[9];
  pp.out = (float*)d_out;

  float* p  = (float*)d_ws;
  pp.xa = p;  p += (size_t)B_*V_*D_;
  pp.xb = p;  p += (size_t)B_*V_*D_;
  pp.xc = p;  p += (size_t)B_*V_*D_;
  pp.y1 = p;  p += (size_t)M_*64;
  pp.zb = p;  p += (size_t)M_*64;
  pp.zc = p;  p += (size_t)M_*64;
  short* sp = (short*)p;
  pp.ZKh = sp;  sp += (size_t)M_*320;
  pp.ZKl = sp;  sp += (size_t)M_*320;
  pp.y2h = sp;  sp += (size_t)M_*128;
  pp.y2l = sp;  sp += (size_t)M_*128;
  pp.h1h = sp;  sp += (size_t)M_*512;
  pp.h1l = sp;  sp += (size_t)M_*512;
  pp.ZtAh = sp; sp += (size_t)M_*64;
  pp.ZtAl = sp; sp += (size_t)M_*64;
  pp.ZtBh = sp; sp += (size_t)M_*64;
  pp.ZtBl = sp; sp += (size_t)M_*64;
  pp.w1h = sp;  sp += 64*64;
  pp.w1l = sp;  sp += 64*64;
  pp.w2h = sp;  sp += 128*320;
  pp.w2l = sp;  sp += 128*320;
  pp.fw1h = sp; sp += 512*128;
  pp.fw1l = sp; sp += 512*128;
  pp.fw2h = sp; sp += 256*512;
  pp.fw2l = sp; sp += 256*512;
  // XK aliased into h1h region (disjoint lifetimes: XK dead before h1 written)
  pp.XKh = pp.h1h;
  pp.XKl = pp.h1h + (size_t)M_*64;
  // barrier state at the tail of our allocations (8-byte aligned)
  pp.bar = (unsigned*)((((size_t)sp) + 255) & ~(size_t)255);

  k_init<<<1, 1, 0, stream>>>(pp.bar);
  k_mega<<<NBLK, 256, 0, stream>>>(pp);
}

// Round 5
// 1265.485 us; speedup vs baseline: 1.2199x; 1.2199x over previous
//
#include <hip/hip_runtime.h>

#define B_ 8
#define V_ 2048
#define D_ 3
#define M_ (B_*V_)   // 16384 rows
#define NBLK 512

typedef __attribute__((ext_vector_type(8))) short short8;
typedef __attribute__((ext_vector_type(4))) float f32x4;

__device__ inline void async_copy16(const void* g, void* lds) {
  __builtin_amdgcn_global_load_lds(
      (const __attribute__((address_space(1))) unsigned int*)g,
      (__attribute__((address_space(3))) unsigned int*)lds, 16, 0, 0);
}

__device__ inline void split_bf16(float v, short& hi, short& lo) {
  unsigned u  = __float_as_uint(v);
  unsigned hb = u & 0xFFFF0000u;
  float d = v - __uint_as_float(hb);
  hi = (short)(hb >> 16);
  lo = (short)(__float_as_uint(d) >> 16);
}

// ---------------------------------------------------------------------------
// Grid barrier v2 (sense-reversing).  Round-4's version ACQUIRE-polled ->
// one L2-invalidate per poll per spinner = coherence storm (65 us/barrier,
// plus it invalidated compute blocks' L2).  v2: RELAXED polls (no cache
// maintenance), ONE acquire fence on exit.  Release semantics on the single
// arrival increment publish this block's stores (L2 writeback once).
// Co-residency: 512 blocks = 2/CU x 256 CU, guaranteed by launch_bounds.
// ---------------------------------------------------------------------------
__device__ inline void grid_sync(unsigned* bar) {
  __syncthreads();
  if (threadIdx.x == 0) {
    unsigned* cnt = bar;
    unsigned* gen = bar + 1;
    unsigned g = __hip_atomic_load(gen, __ATOMIC_RELAXED, __HIP_MEMORY_SCOPE_AGENT);
    unsigned a = __hip_atomic_fetch_add(cnt, 1u, __ATOMIC_ACQ_REL, __HIP_MEMORY_SCOPE_AGENT);
    if (a == NBLK - 1) {   // last to arrive: reset + publish new generation
      __hip_atomic_store(cnt, 0u, __ATOMIC_RELAXED, __HIP_MEMORY_SCOPE_AGENT);
      __hip_atomic_store(gen, g + 1u, __ATOMIC_RELEASE, __HIP_MEMORY_SCOPE_AGENT);
    } else {
      while (__hip_atomic_load(gen, __ATOMIC_RELAXED, __HIP_MEMORY_SCOPE_AGENT) == g)
        __builtin_amdgcn_s_sleep(16);
      __builtin_amdgcn_fence(__ATOMIC_ACQUIRE, "agent");   // one invalidate
    }
  }
  __syncthreads();
}

__global__ void k_init(unsigned* bar) { bar[0] = 0u; bar[1] = 0u; }

struct Params {
  const float *x, *L, *w1, *b1, *w2, *b2, *fw1, *fb1, *fw2, *fb2;
  float *out;
  float *xa, *xb, *xc, *y1, *zb, *zc;
  short *ZKh, *ZKl, *y2h, *y2l, *h1h, *h1l;
  short *ZtAh, *ZtAl, *ZtBh, *ZtBl;
  short *w1h, *w1l, *w2h, *w2l, *fw1h, *fw1l, *fw2h, *fw2l;
  short *XKh, *XKl;
  unsigned *bar;
};

// LDS union: max(24 KB cheby1, 48 KB cheby2, 32 KB gemm) = 48 KB
union SMem {
  float sx[3][V_];                                         // cheby1: 24 KB
  struct { float a[2][32*64]; short bh[2][64*64]; short bl[2][64*64]; } c2;  // 48 KB
  struct { short ah[64*64]; short al[64*64]; short wh[64*64]; short wl[64*64]; } g; // 32 KB
};

// ---------------------------------------------------------------------------
// prep phase: XK slot0 (+zero pads) + xa transpose + all weight splits.
// ---------------------------------------------------------------------------
__device__ void prep_phase(const Params& p) {
  for (int c = 0; c < 10; c++) {
    int i = c*131072 + blockIdx.x*256 + threadIdx.x;
    short hi, lo;
    if (i < M_*64) {   // XK: row r = i>>6, slot s = i&63; slot = f*6+k, k=0 live
      int r = i >> 6, s = i & 63;
      float val = 0.f;
      if (s == 0 || s == 6 || s == 12) {
        int f = s / 6;
        int b = r >> 11, v = r & (V_-1);
        val = p.x[((size_t)b*D_ + f)*V_ + v];
        p.xa[(size_t)r*3 + f] = val;
      }
      split_bf16(val, hi, lo);
      p.XKh[i] = hi; p.XKl[i] = lo;
    } else {
      int j = i - M_*64;
      if (j < 4096) {          // w1: [64,18] -> [64,64] padded
        int k = j & 63;
        float v = (k < 18) ? p.w1[(j>>6)*18 + k] : 0.f;
        split_bf16(v, hi, lo); p.w1h[j] = hi; p.w1l[j] = lo;
      } else if ((j -= 4096) < 40960) {
        split_bf16(p.w2[j],  hi, lo); p.w2h[j]=hi;  p.w2l[j]=lo;
      } else if ((j -= 40960) < 65536) {
        split_bf16(p.fw1[j], hi, lo); p.fw1h[j]=hi; p.fw1l[j]=lo;
      } else if ((j -= 65536) < 131072) {
        split_bf16(p.fw2[j], hi, lo); p.fw2h[j]=hi; p.fw2l[j]=lo;
      }
    }
  }
}

// ---------------------------------------------------------------------------
// cheby1 phase: xn = alpha*(L@xc) - beta*xp.  512 blocks: 32 rows/block,
// 8 rows/wave, batch pinned (b = bid&7).  FULL unroll of the 8-iteration
// k-loop -> up to 64 independent L float4 loads in flight per wave
// (latency fix).  Per-row FMA tree unchanged -> bit-identical results.
// ---------------------------------------------------------------------------
__device__ void cheby1_phase(const Params& p, SMem& sm,
    const float* xc, const float* xp, float* xn,
    float alpha, float beta, int kidx) {
  int b  = blockIdx.x & 7;
  int r0 = (blockIdx.x >> 3) * 32;   // 64 row-tiles of 32
  const float* xcb = xc + (size_t)b*V_*D_;
  for (int i = threadIdx.x; i < V_*D_; i += 256) {
    int u = i / 3, f = i - u*3;
    sm.sx[f][u] = xcb[i];
  }
  __syncthreads();
  int w = threadIdx.x >> 6, lane = threadIdx.x & 63;
  const float4* X0 = (const float4*)sm.sx[0];
  const float4* X1 = (const float4*)sm.sx[1];
  const float4* X2 = (const float4*)sm.sx[2];
  int rbase = r0 + w*8;
  const float4* Lr = (const float4*)(p.L + ((size_t)b*V_ + rbase)*V_);

  float acc[8][3];
  #pragma unroll
  for (int rr = 0; rr < 8; rr++) { acc[rr][0]=0.f; acc[rr][1]=0.f; acc[rr][2]=0.f; }

  #pragma unroll
  for (int it = 0; it < 8; it++) {
    int u4 = it*64 + lane;
    float4 x0 = X0[u4], x1 = X1[u4], x2 = X2[u4];
    #pragma unroll
    for (int rr = 0; rr < 8; rr++) {
      float4 lv = Lr[(size_t)rr*512 + u4];
      acc[rr][0] = fmaf(lv.x,x0.x,fmaf(lv.y,x0.y,fmaf(lv.z,x0.z,fmaf(lv.w,x0.w,acc[rr][0]))));
      acc[rr][1] = fmaf(lv.x,x1.x,fmaf(lv.y,x1.y,fmaf(lv.z,x1.z,fmaf(lv.w,x1.w,acc[rr][1]))));
      acc[rr][2] = fmaf(lv.x,x2.x,fmaf(lv.y,x2.y,fmaf(lv.z,x2.z,fmaf(lv.w,x2.w,acc[rr][2]))));
    }
  }
  #pragma unroll
  for (int off = 32; off > 0; off >>= 1)
    #pragma unroll
    for (int rr = 0; rr < 8; rr++)
      #pragma unroll
      for (int f = 0; f < 3; f++)
        acc[rr][f] += __shfl_down(acc[rr][f], off);

  if (lane == 0) {
    size_t base = ((size_t)b*V_ + rbase)*3;   // 24 consecutive floats
    float v[24];
    #pragma unroll
    for (int rr = 0; rr < 8; rr++)
      #pragma unroll
      for (int f = 0; f < 3; f++)
        v[rr*3+f] = alpha*acc[rr][f];
    if (beta != 0.f) {
      const float4* xp4 = (const float4*)(xp + base);
      #pragma unroll
      for (int q = 0; q < 6; q++) {
        float4 pv = xp4[q];
        v[q*4+0] -= beta*pv.x; v[q*4+1] -= beta*pv.y;
        v[q*4+2] -= beta*pv.z; v[q*4+3] -= beta*pv.w;
      }
    }
    float4* xn4 = (float4*)(xn + base);
    #pragma unroll
    for (int q = 0; q < 6; q++)
      xn4[q] = make_float4(v[q*4], v[q*4+1], v[q*4+2], v[q*4+3]);
    #pragma unroll
    for (int rr = 0; rr < 8; rr++)
      #pragma unroll
      for (int f = 0; f < 3; f++) {
        short hi, lo; split_bf16(v[rr*3+f], hi, lo);
        size_t o = ((size_t)b*V_ + rbase + rr)*64 + f*6 + kidx;
        p.XKh[o] = hi; p.XKl[o] = lo;
      }
  }
}

// ---------------------------------------------------------------------------
// cheby2 phase: Zn = alpha*(L @ z) - beta*Zp ; split-bf16 MFMA.
// 32-row x 64-col tiles, 512 blocks, double-buffered.
// ---------------------------------------------------------------------------
__device__ void cheby2_phase(const Params& p, SMem& sm,
    const short* Zth, const short* Ztl, const float* Zp,
    float* Zn, short* Znth, short* Zntl,
    float alpha, float beta, int kidx) {
  int b  = blockIdx.x & 7;              // batch -> XCD pin
  int r0 = (blockIdx.x >> 3) * 32;      // 64 row-tiles
  const float* Lb   = p.L + (size_t)b*V_*V_;
  const short* Zthb = Zth + (size_t)b*64*V_;
  const short* Ztlb = Ztl + (size_t)b*64*V_;

  int tid  = threadIdx.x;
  int w    = tid >> 6;
  int lane = tid & 63;
  int lm   = lane & 15;
  int quad = lane >> 4;
  int cbase = w * 16;

  int f1  = tid + 256;
  int rA0 = tid >> 4, cA0 = (tid & 15) ^ (rA0 & 15);
  int rA1 = f1 >> 4,  cA1 = (f1 & 15) ^ (rA1 & 15);
  size_t gA0 = (size_t)(r0 + rA0)*V_ + cA0*4;
  size_t gA1 = (size_t)(r0 + rA1)*V_ + cA1*4;
  int nB0 = tid >> 3, cB0 = (tid & 7) ^ (nB0 & 7);
  int nB1 = f1 >> 3,  cB1 = (f1 & 7) ^ (nB1 & 7);
  size_t gB0 = (size_t)nB0*V_ + cB0*8;
  size_t gB1 = (size_t)nB1*V_ + cB1*8;

  auto stage = [&](int bb, int k0) {
    async_copy16(Lb   + gA0 + k0, &sm.c2.a[bb][tid*4]);
    async_copy16(Lb   + gA1 + k0, &sm.c2.a[bb][f1*4]);
    async_copy16(Zthb + gB0 + k0, &sm.c2.bh[bb][tid*8]);
    async_copy16(Ztlb + gB0 + k0, &sm.c2.bl[bb][tid*8]);
    async_copy16(Zthb + gB1 + k0, &sm.c2.bh[bb][f1*8]);
    async_copy16(Ztlb + gB1 + k0, &sm.c2.bl[bb][f1*8]);
  };

  f32x4 acc[2] = {{0.f,0.f,0.f,0.f},{0.f,0.f,0.f,0.f}};

  stage(0, 0);

  for (int s = 0; s < V_/64; s++) {
    int bb = s & 1;
    asm volatile("s_waitcnt vmcnt(0)" ::: "memory");
    __builtin_amdgcn_s_barrier();
    __builtin_amdgcn_sched_barrier(0);
    if (s < V_/64 - 1) stage(bb ^ 1, (s+1)*64);

    const f32x4*  sAv  = (const f32x4*)sm.c2.a[bb];
    const short8* sBhv = (const short8*)sm.c2.bh[bb];
    const short8* sBlv = (const short8*)sm.c2.bl[bb];

    #pragma unroll
    for (int ks = 0; ks < 2; ks++) {
      int koff = ks * 32;
      short8 ah[2], al[2];
      #pragma unroll
      for (int t = 0; t < 2; t++) {
        int r = t*16 + lm;
        int ca = (koff >> 2) + 2*quad;
        f32x4 a0 = sAv[r*16 + (ca ^ (r & 15))];
        f32x4 a1 = sAv[r*16 + ((ca + 1) ^ (r & 15))];
        float av[8] = {a0.x, a0.y, a0.z, a0.w, a1.x, a1.y, a1.z, a1.w};
        #pragma unroll
        for (int j = 0; j < 8; j++) {
          short hi, lo; split_bf16(av[j], hi, lo);
          ah[t][j] = hi; al[t][j] = lo;
        }
      }
      int cb = (koff >> 3) + quad;
      int n = cbase + lm;
      short8 bh = sBhv[n*8 + (cb ^ (n & 7))];
      short8 bl = sBlv[n*8 + (cb ^ (n & 7))];
      __builtin_amdgcn_s_setprio(1);
      #pragma unroll
      for (int t = 0; t < 2; t++) {
        acc[t] = __builtin_amdgcn_mfma_f32_16x16x32_bf16(ah[t], bh, acc[t], 0, 0, 0);
        acc[t] = __builtin_amdgcn_mfma_f32_16x16x32_bf16(ah[t], bl, acc[t], 0, 0, 0);
        acc[t] = __builtin_amdgcn_mfma_f32_16x16x32_bf16(al[t], bh, acc[t], 0, 0, 0);
      }
      __builtin_amdgcn_s_setprio(0);
    }
  }

  int n = cbase + lm;
  #pragma unroll
  for (int t = 0; t < 2; t++) {
    #pragma unroll
    for (int i = 0; i < 4; i++) {
      int r = r0 + t*16 + quad*4 + i;
      size_t rowb = (size_t)b*V_ + r;
      float v = alpha * acc[t][i];
      if (beta != 0.f) v -= beta * Zp[rowb*64 + n];
      Zn[rowb*64 + n] = v;
      short hi, lo; split_bf16(v, hi, lo);
      size_t ok = rowb*320 + (size_t)n*5 + kidx;
      p.ZKh[ok] = hi; p.ZKl[ok] = lo;
      size_t o = ((size_t)b*64 + n)*V_ + r;
      Znth[o] = hi; Zntl[o] = lo;
    }
  }
}

// ---------------------------------------------------------------------------
// gemm_tile: one 64x64 output tile of C = relu(A[M,K] @ W[N,K]^T + bias).
// ---------------------------------------------------------------------------
__device__ __forceinline__ void gemm_tile(
    const short* __restrict__ Ah, const short* __restrict__ Al,
    const short* __restrict__ Wh, const short* __restrict__ Wl,
    const float* __restrict__ bias, int N, int K, int row0, int col0,
    short* sAh, short* sAl, short* sWh, short* sWl,
    float* __restrict__ Cf, short* __restrict__ Ch, short* __restrict__ Cl,
    short* __restrict__ Ph, short* __restrict__ Pl, int packMul, int packStride,
    short* __restrict__ Th, short* __restrict__ Tl) {
  int tid = threadIdx.x, w = tid >> 6, lane = tid & 63;
  int lm = lane & 15, quad = lane >> 4;
  int wm = (w & 1) * 32, wn = (w >> 1) * 32;

  __syncthreads();   // previous phase/tile may still be reading this LDS

  const short8* vAh = (const short8*)sAh;
  const short8* vAl = (const short8*)sAl;
  const short8* vWh = (const short8*)sWh;
  const short8* vWl = (const short8*)sWl;

  f32x4 acc[2][2] = {{{0.f,0.f,0.f,0.f},{0.f,0.f,0.f,0.f}},
                     {{0.f,0.f,0.f,0.f},{0.f,0.f,0.f,0.f}}};

  for (int k0 = 0; k0 < K; k0 += 64) {
    if (k0) __syncthreads();
    #pragma unroll
    for (int t = 0; t < 2; t++) {
      int f = t*256 + tid;
      int r = f >> 3, pp = f & 7;
      int c = pp ^ (r & 7);
      size_t goA = (size_t)(row0 + r)*K + k0 + c*8;
      size_t goW = (size_t)(col0 + r)*K + k0 + c*8;
      async_copy16(Ah + goA, &sAh[f*8]);
      async_copy16(Al + goA, &sAl[f*8]);
      async_copy16(Wh + goW, &sWh[f*8]);
      async_copy16(Wl + goW, &sWl[f*8]);
    }
    __syncthreads();

    #pragma unroll
    for (int ks = 0; ks < 2; ks++) {
      int kc = ks*4 + quad;
      short8 a_h[2], a_l[2], b_h[2], b_l[2];
      #pragma unroll
      for (int i = 0; i < 2; i++) {
        int m = wm + i*16 + lm;
        a_h[i] = vAh[m*8 + (kc ^ (m & 7))];
        a_l[i] = vAl[m*8 + (kc ^ (m & 7))];
      }
      #pragma unroll
      for (int j = 0; j < 2; j++) {
        int n = wn + j*16 + lm;
        b_h[j] = vWh[n*8 + (kc ^ (n & 7))];
        b_l[j] = vWl[n*8 + (kc ^ (n & 7))];
      }
      #pragma unroll
      for (int i = 0; i < 2; i++)
        #pragma unroll
        for (int j = 0; j < 2; j++) {
          acc[i][j] = __builtin_amdgcn_mfma_f32_16x16x32_bf16(a_h[i], b_h[j], acc[i][j], 0, 0, 0);
          acc[i][j] = __builtin_amdgcn_mfma_f32_16x16x32_bf16(a_h[i], b_l[j], acc[i][j], 0, 0, 0);
          acc[i][j] = __builtin_amdgcn_mfma_f32_16x16x32_bf16(a_l[i], b_h[j], acc[i][j], 0, 0, 0);
        }
    }
  }

  #pragma unroll
  for (int i = 0; i < 2; i++)
    #pragma unroll
    for (int j = 0; j < 2; j++) {
      int col = col0 + wn + j*16 + lm;
      float bj = bias[col];
      #pragma unroll
      for (int g = 0; g < 4; g++) {
        int row = row0 + wm + i*16 + quad*4 + g;
        float v = acc[i][j][g] + bj;
        v = v > 0.f ? v : 0.f;
        if (Cf) Cf[(size_t)row*N + col] = v;
        short hi, lo;
        if (Ch || Ph || Th) split_bf16(v, hi, lo);
        if (Ch) {
          Ch[(size_t)row*N + col] = hi;
          Cl[(size_t)row*N + col] = lo;
        }
        if (Ph) {
          size_t o = (size_t)row*packStride + (size_t)col*packMul;
          Ph[o] = hi; Pl[o] = lo;
        }
        if (Th) {  // transposed [B,64,V] (N==64)
          int bb = row >> 11, vv = row & (V_-1);
          size_t o = ((size_t)bb*64 + col)*V_ + vv;
          Th[o] = hi; Tl[o] = lo;
        }
      }
    }
}

// ---------------------------------------------------------------------------
// The whole network in ONE kernel: 512 blocks x 256 threads (all resident),
// 13 phases separated by the fixed grid barrier.
// ---------------------------------------------------------------------------
__global__ __launch_bounds__(256, 2) void k_mega(Params p) {
  __shared__ SMem sm;

  // P0: prep
  prep_phase(p);
  grid_sync(p.bar);

  // P1..P5: cheby1 chain  (xa -> xb -> xc -> xa -> xb -> xc)
  cheby1_phase(p, sm, p.xa, p.xa, p.xb, 1.f, 0.f, 1); grid_sync(p.bar);
  cheby1_phase(p, sm, p.xb, p.xa, p.xc, 2.f, 1.f, 2); grid_sync(p.bar);
  cheby1_phase(p, sm, p.xc, p.xb, p.xa, 2.f, 1.f, 3); grid_sync(p.bar);
  cheby1_phase(p, sm, p.xa, p.xc, p.xb, 2.f, 1.f, 4); grid_sync(p.bar);
  cheby1_phase(p, sm, p.xb, p.xa, p.xc, 2.f, 1.f, 5); grid_sync(p.bar);

  // P6: y1 = relu(XK @ w1^T + b1)  (+ ZK slot0 pack + ZtA transposed split)
  if (blockIdx.x < 256)
    gemm_tile(p.XKh, p.XKl, p.w1h, p.w1l, p.b1, 64, 64, blockIdx.x*64, 0,
              sm.g.ah, sm.g.al, sm.g.wh, sm.g.wl,
              p.y1, nullptr, nullptr, p.ZKh, p.ZKl, 5, 320, p.ZtAh, p.ZtAl);
  grid_sync(p.bar);

  // P7..P10: cheby2 chain
  cheby2_phase(p, sm, p.ZtAh, p.ZtAl, p.y1, p.zb, p.ZtBh, p.ZtBl, 1.f, 0.f, 1); grid_sync(p.bar);
  cheby2_phase(p, sm, p.ZtBh, p.ZtBl, p.y1, p.zc, p.ZtAh, p.ZtAl, 2.f, 1.f, 2); grid_sync(p.bar);
  cheby2_phase(p, sm, p.ZtAh, p.ZtAl, p.zb, p.y1, p.ZtBh, p.ZtBl, 2.f, 1.f, 3); grid_sync(p.bar);
  cheby2_phase(p, sm, p.ZtBh, p.ZtBl, p.zc, p.zb, p.ZtAh, p.ZtAl, 2.f, 1.f, 4); grid_sync(p.bar);

  // P11: y2 = relu(ZK @ w2^T + b2)   512 tiles (256 x 2)
  {
    int bm = blockIdx.x & 255, bn = blockIdx.x >> 8;
    gemm_tile(p.ZKh, p.ZKl, p.w2h, p.w2l, p.b2, 128, 320, bm*64, bn*64,
              sm.g.ah, sm.g.al, sm.g.wh, sm.g.wl,
              nullptr, p.y2h, p.y2l, nullptr, nullptr, 0, 0, nullptr, nullptr);
  }
  grid_sync(p.bar);

  // P12: h1 = relu(y2 @ fw1^T + fb1)   2048 tiles -> 4 per block
  for (int t = 0; t < 4; t++) {
    int id = blockIdx.x + t*512;
    int bm = id & 255, bn = id >> 8;
    gemm_tile(p.y2h, p.y2l, p.fw1h, p.fw1l, p.fb1, 512, 128, bm*64, bn*64,
              sm.g.ah, sm.g.al, sm.g.wh, sm.g.wl,
              nullptr, p.h1h, p.h1l, nullptr, nullptr, 0, 0, nullptr, nullptr);
  }
  grid_sync(p.bar);

  // P13: out = relu(h1 @ fw2^T + fb2)  1024 tiles -> 2 per block
  for (int t = 0; t < 2; t++) {
    int id = blockIdx.x + t*512;
    int bm = id & 255, bn = id >> 8;
    gemm_tile(p.h1h, p.h1l, p.fw2h, p.fw2l, p.fb2, 256, 512, bm*64, bn*64,
              sm.g.ah, sm.g.al, sm.g.wh, sm.g.wl,
              p.out, nullptr, nullptr, nullptr, nullptr, 0, 0, nullptr, nullptr);
  }
}

// ---------------------------------------------------------------------------
extern "C" void kernel_launch(void* const* d_in, const int* in_sizes, int n_in,
                              void* d_out, int out_size, void* d_ws, size_t ws_size,
                              hipStream_t stream) {
  Params pp;
  pp.x   = (const float*)d_in[0];
  pp.L   = (const float*)d_in[1];
  pp.w1  = (const float*)d_in[2];
  pp.b1  = (const float*)d_in[3];
  pp.w2  = (const float*)d_in[4];
  pp.b2  = (const float*)d_in[5];
  pp.fw1 = (const float*)d_in[6];
  pp.fb1 = (const float*)d_in[7];
  pp.fw2 = (const float*)d_in[8];
  pp.fb2 = (const float*)d_in[9];
  pp.out = (float*)d_out;

  float* p  = (float*)d_ws;
  pp.xa = p;  p += (size_t)B_*V_*D_;
  pp.xb = p;  p += (size_t)B_*V_*D_;
  pp.xc = p;  p += (size_t)B_*V_*D_;
  pp.y1 = p;  p += (size_t)M_*64;
  pp.zb = p;  p += (size_t)M_*64;
  pp.zc = p;  p += (size_t)M_*64;
  short* sp = (short*)p;
  pp.ZKh = sp;  sp += (size_t)M_*320;
  pp.ZKl = sp;  sp += (size_t)M_*320;
  pp.y2h = sp;  sp += (size_t)M_*128;
  pp.y2l = sp;  sp += (size_t)M_*128;
  pp.h1h = sp;  sp += (size_t)M_*512;
  pp.h1l = sp;  sp += (size_t)M_*512;
  pp.ZtAh = sp; sp += (size_t)M_*64;
  pp.ZtAl = sp; sp += (size_t)M_*64;
  pp.ZtBh = sp; sp += (size_t)M_*64;
  pp.ZtBl = sp; sp += (size_t)M_*64;
  pp.w1h = sp;  sp += 64*64;
  pp.w1l = sp;  sp += 64*64;
  pp.w2h = sp;  sp += 128*320;
  pp.w2l = sp;  sp += 128*320;
  pp.fw1h = sp; sp += 512*128;
  pp.fw1l = sp; sp += 512*128;
  pp.fw2h = sp; sp += 256*512;
  pp.fw2l = sp; sp += 256*512;
  // XK aliased into h1h region (disjoint lifetimes: XK dead before h1 written)
  pp.XKh = pp.h1h;
  pp.XKl = pp.h1h + (size_t)M_*64;
  // barrier state at the tail of our allocations (cache-line aligned)
  pp.bar = (unsigned*)((((size_t)sp) + 255) & ~(size_t)255);

  k_init<<<1, 1, 0, stream>>>(pp.bar);
  k_mega<<<NBLK, 256, 0, stream>>>(pp);
}

// Round 6
// 698.412 us; speedup vs baseline: 2.2103x; 1.8119x over previous
//
#include <hip/hip_runtime.h>

#define B_ 8
#define V_ 2048
#define D_ 3
#define M_ (B_*V_)   // 16384 rows

typedef __attribute__((ext_vector_type(8))) short short8;
typedef __attribute__((ext_vector_type(4))) float f32x4;

__device__ inline void async_copy16(const void* g, void* lds) {
  __builtin_amdgcn_global_load_lds(
      (const __attribute__((address_space(1))) unsigned int*)g,
      (__attribute__((address_space(3))) unsigned int*)lds, 16, 0, 0);
}

__device__ inline void split_bf16(float v, short& hi, short& lo) {
  unsigned u  = __float_as_uint(v);
  unsigned hb = u & 0xFFFF0000u;
  float d = v - __uint_as_float(hb);
  hi = (short)(hb >> 16);
  lo = (short)(__float_as_uint(d) >> 16);
}

// ---------------------------------------------------------------------------
// k_prep: materialize XK (slot 0 from x-transpose, pads zero) + xa transpose
// + split all 4 weight matrices.  One launch, 5040 blocks x 256.
// ---------------------------------------------------------------------------
__global__ __launch_bounds__(256) void k_prep(
    const float* __restrict__ x,
    const float* __restrict__ w1, const float* __restrict__ w2,
    const float* __restrict__ fw1, const float* __restrict__ fw2,
    float* __restrict__ xa,
    short* __restrict__ XKh, short* __restrict__ XKl,
    short* __restrict__ w1h, short* __restrict__ w1l,
    short* __restrict__ w2h, short* __restrict__ w2l,
    short* __restrict__ fw1h, short* __restrict__ fw1l,
    short* __restrict__ fw2h, short* __restrict__ fw2l) {
  int i = blockIdx.x * 256 + threadIdx.x;
  short hi, lo;
  if (i < M_*64) {   // XK: row r = i>>6, slot s = i&63; slot = f*6+k, k=0 live
    int r = i >> 6, s = i & 63;
    float val = 0.f;
    if (s == 0 || s == 6 || s == 12) {
      int f = s / 6;
      int b = r >> 11, v = r & (V_-1);
      val = x[((size_t)b*D_ + f)*V_ + v];
      xa[(size_t)r*3 + f] = val;
    }
    split_bf16(val, hi, lo);
    XKh[i] = hi; XKl[i] = lo;
    return;
  }
  i -= M_*64;
  if (i < 4096) {          // w1: [64,18] -> [64,64] padded
    int n = i >> 6, k = i & 63;
    float v = (k < 18) ? w1[n*18 + k] : 0.f;
    split_bf16(v, hi, lo); w1h[i] = hi; w1l[i] = lo; return;
  }
  i -= 4096;
  if (i < 40960) { split_bf16(w2[i],  hi, lo); w2h[i]=hi;  w2l[i]=lo;  return; }
  i -= 40960;
  if (i < 65536) { split_bf16(fw1[i], hi, lo); fw1h[i]=hi; fw1l[i]=lo; return; }
  i -= 65536;
  if (i < 131072){ split_bf16(fw2[i], hi, lo); fw2h[i]=hi; fw2l[i]=lo; return; }
}

// ---------------------------------------------------------------------------
// k_cheby1: one recurrence step (3 features): xn = alpha*(L@xc) - beta*xp.
// 1024 blocks x 256: 16 rows/block, 4 rows/wave, batch pinned to XCD.
// ---------------------------------------------------------------------------
__global__ __launch_bounds__(256) void k_cheby1(const float* __restrict__ L,
    const float* __restrict__ xc, const float* __restrict__ xp,
    float* __restrict__ xn, short* __restrict__ XKh, short* __restrict__ XKl,
    float alpha, float beta, int kidx) {
  __shared__ float sx[3][V_];  // 24 KB
  int b  = blockIdx.x & 7;          // batch -> XCD pin
  int r0 = (blockIdx.x >> 3) * 16;  // 128 tiles
  const float* xcb = xc + (size_t)b*V_*D_;
  for (int i = threadIdx.x; i < V_*D_; i += 256) {
    int u = i / 3, f = i - u*3;
    sx[f][u] = xcb[i];
  }
  __syncthreads();
  int w = threadIdx.x >> 6, lane = threadIdx.x & 63;
  const float4* X0 = (const float4*)sx[0];
  const float4* X1 = (const float4*)sx[1];
  const float4* X2 = (const float4*)sx[2];
  int rbase = r0 + w*4;
  const float4* Lr[4];
  #pragma unroll
  for (int rr = 0; rr < 4; rr++)
    Lr[rr] = (const float4*)(L + ((size_t)b*V_ + rbase + rr)*V_);

  float acc[4][3] = {{0.f,0.f,0.f},{0.f,0.f,0.f},{0.f,0.f,0.f},{0.f,0.f,0.f}};

  #pragma unroll 2
  for (int it = 0; it < 8; it++) {
    int u4 = it*64 + lane;
    float4 x0 = X0[u4], x1 = X1[u4], x2 = X2[u4];
    #pragma unroll
    for (int rr = 0; rr < 4; rr++) {
      float4 lv = Lr[rr][u4];
      acc[rr][0] = fmaf(lv.x,x0.x,fmaf(lv.y,x0.y,fmaf(lv.z,x0.z,fmaf(lv.w,x0.w,acc[rr][0]))));
      acc[rr][1] = fmaf(lv.x,x1.x,fmaf(lv.y,x1.y,fmaf(lv.z,x1.z,fmaf(lv.w,x1.w,acc[rr][1]))));
      acc[rr][2] = fmaf(lv.x,x2.x,fmaf(lv.y,x2.y,fmaf(lv.z,x2.z,fmaf(lv.w,x2.w,acc[rr][2]))));
    }
  }
  #pragma unroll
  for (int off = 32; off > 0; off >>= 1)
    #pragma unroll
    for (int rr = 0; rr < 4; rr++)
      #pragma unroll
      for (int f = 0; f < 3; f++)
        acc[rr][f] += __shfl_down(acc[rr][f], off);

  if (lane == 0) {
    size_t base = ((size_t)b*V_ + rbase)*3;   // 12 consecutive floats, 16B-aligned
    float v[12];
    #pragma unroll
    for (int rr = 0; rr < 4; rr++)
      #pragma unroll
      for (int f = 0; f < 3; f++)
        v[rr*3+f] = alpha*acc[rr][f];
    if (beta != 0.f) {
      const float4* xp4 = (const float4*)(xp + base);
      float4 p0 = xp4[0], p1 = xp4[1], p2 = xp4[2];
      v[0] -= beta*p0.x; v[1]  -= beta*p0.y; v[2]  -= beta*p0.z; v[3]  -= beta*p0.w;
      v[4] -= beta*p1.x; v[5]  -= beta*p1.y; v[6]  -= beta*p1.z; v[7]  -= beta*p1.w;
      v[8] -= beta*p2.x; v[9]  -= beta*p2.y; v[10] -= beta*p2.z; v[11] -= beta*p2.w;
    }
    float4* xn4 = (float4*)(xn + base);
    xn4[0] = make_float4(v[0], v[1], v[2],  v[3]);
    xn4[1] = make_float4(v[4], v[5], v[6],  v[7]);
    xn4[2] = make_float4(v[8], v[9], v[10], v[11]);
    #pragma unroll
    for (int rr = 0; rr < 4; rr++)
      #pragma unroll
      for (int f = 0; f < 3; f++) {
        short hi, lo; split_bf16(v[rr*3+f], hi, lo);
        size_t o = ((size_t)b*V_ + rbase + rr)*64 + f*6 + kidx;
        XKh[o] = hi; XKl[o] = lo;
      }
  }
}

// ---------------------------------------------------------------------------
// k_cheby2_mfma: Zn = alpha*(L @ z) - beta*Zp ; split-bf16 MFMA.
// 32-row x 64-col tiles -> 512 blocks, batch pinned to XCD, double-buffered.
// (byte-identical to the round-2 verified kernel)
// ---------------------------------------------------------------------------
__global__ __launch_bounds__(256) void k_cheby2_mfma(const float* __restrict__ L,
    const short* __restrict__ Zth, const short* __restrict__ Ztl,
    const float* __restrict__ Zp,
    float* __restrict__ Zn, short* __restrict__ ZKh, short* __restrict__ ZKl,
    short* __restrict__ Znth, short* __restrict__ Zntl,
    float alpha, float beta, int kidx) {
  __shared__ float sA[2][32*64];    // L tile  [r][k], chunk-swizzled, 2x8 KB
  __shared__ short sBh[2][64*64];   // Zt hi   [n][k], chunk-swizzled, 2x8 KB
  __shared__ short sBl[2][64*64];   // Zt lo   [n][k], chunk-swizzled, 2x8 KB

  int b  = blockIdx.x & 7;              // batch -> XCD pin
  int r0 = (blockIdx.x >> 3) * 32;      // 64 row-tiles
  const float* Lb   = L   + (size_t)b*V_*V_;
  const short* Zthb = Zth + (size_t)b*64*V_;
  const short* Ztlb = Ztl + (size_t)b*64*V_;

  int tid  = threadIdx.x;
  int w    = tid >> 6;
  int lane = tid & 63;
  int lm   = lane & 15;
  int quad = lane >> 4;
  int cbase = w * 16;

  int f1  = tid + 256;
  int rA0 = tid >> 4, cA0 = (tid & 15) ^ (rA0 & 15);
  int rA1 = f1 >> 4,  cA1 = (f1 & 15) ^ (rA1 & 15);
  size_t gA0 = (size_t)(r0 + rA0)*V_ + cA0*4;
  size_t gA1 = (size_t)(r0 + rA1)*V_ + cA1*4;
  int nB0 = tid >> 3, cB0 = (tid & 7) ^ (nB0 & 7);
  int nB1 = f1 >> 3,  cB1 = (f1 & 7) ^ (nB1 & 7);
  size_t gB0 = (size_t)nB0*V_ + cB0*8;
  size_t gB1 = (size_t)nB1*V_ + cB1*8;

  auto stage = [&](int bb, int k0) {
    async_copy16(Lb   + gA0 + k0, &sA[bb][tid*4]);
    async_copy16(Lb   + gA1 + k0, &sA[bb][f1*4]);
    async_copy16(Zthb + gB0 + k0, &sBh[bb][tid*8]);
    async_copy16(Ztlb + gB0 + k0, &sBl[bb][tid*8]);
    async_copy16(Zthb + gB1 + k0, &sBh[bb][f1*8]);
    async_copy16(Ztlb + gB1 + k0, &sBl[bb][f1*8]);
  };

  f32x4 acc[2] = {{0.f,0.f,0.f,0.f},{0.f,0.f,0.f,0.f}};

  stage(0, 0);

  for (int s = 0; s < V_/64; s++) {
    int bb = s & 1;
    asm volatile("s_waitcnt vmcnt(0)" ::: "memory");
    __builtin_amdgcn_s_barrier();
    __builtin_amdgcn_sched_barrier(0);
    if (s < V_/64 - 1) stage(bb ^ 1, (s+1)*64);

    const f32x4*  sAv  = (const f32x4*)sA[bb];
    const short8* sBhv = (const short8*)sBh[bb];
    const short8* sBlv = (const short8*)sBl[bb];

    #pragma unroll
    for (int ks = 0; ks < 2; ks++) {
      int koff = ks * 32;
      short8 ah[2], al[2];
      #pragma unroll
      for (int t = 0; t < 2; t++) {
        int r = t*16 + lm;
        int ca = (koff >> 2) + 2*quad;
        f32x4 a0 = sAv[r*16 + (ca ^ (r & 15))];
        f32x4 a1 = sAv[r*16 + ((ca + 1) ^ (r & 15))];
        float av[8] = {a0.x, a0.y, a0.z, a0.w, a1.x, a1.y, a1.z, a1.w};
        #pragma unroll
        for (int j = 0; j < 8; j++) {
          short hi, lo; split_bf16(av[j], hi, lo);
          ah[t][j] = hi; al[t][j] = lo;
        }
      }
      int cb = (koff >> 3) + quad;
      int n = cbase + lm;
      short8 bh = sBhv[n*8 + (cb ^ (n & 7))];
      short8 bl = sBlv[n*8 + (cb ^ (n & 7))];
      __builtin_amdgcn_s_setprio(1);
      #pragma unroll
      for (int t = 0; t < 2; t++) {
        acc[t] = __builtin_amdgcn_mfma_f32_16x16x32_bf16(ah[t], bh, acc[t], 0, 0, 0);
        acc[t] = __builtin_amdgcn_mfma_f32_16x16x32_bf16(ah[t], bl, acc[t], 0, 0, 0);
        acc[t] = __builtin_amdgcn_mfma_f32_16x16x32_bf16(al[t], bh, acc[t], 0, 0, 0);
      }
      __builtin_amdgcn_s_setprio(0);
    }
  }

  int n = cbase + lm;
  #pragma unroll
  for (int t = 0; t < 2; t++) {
    #pragma unroll
    for (int i = 0; i < 4; i++) {
      int r = r0 + t*16 + quad*4 + i;
      size_t rowb = (size_t)b*V_ + r;
      float v = alpha * acc[t][i];
      if (beta != 0.f) v -= beta * Zp[rowb*64 + n];
      Zn[rowb*64 + n] = v;
      short hi, lo; split_bf16(v, hi, lo);
      size_t ok = rowb*320 + (size_t)n*5 + kidx;
      ZKh[ok] = hi; ZKl[ok] = lo;
      size_t o = ((size_t)b*64 + n)*V_ + r;
      Znth[o] = hi; Zntl[o] = lo;
    }
  }
}

// ---------------------------------------------------------------------------
// gemm_tile: one 64x64 output tile of C = relu(A[M,K] @ W[N,K]^T + bias).
// ---------------------------------------------------------------------------
__device__ __forceinline__ void gemm_tile(
    const short* __restrict__ Ah, const short* __restrict__ Al,
    const short* __restrict__ Wh, const short* __restrict__ Wl,
    const float* __restrict__ bias, int N, int K, int row0, int col0,
    short* sAh, short* sAl, short* sWh, short* sWl,
    float* __restrict__ Cf, short* __restrict__ Ch, short* __restrict__ Cl,
    short* __restrict__ Ph, short* __restrict__ Pl, int packMul, int packStride,
    short* __restrict__ Th, short* __restrict__ Tl) {
  int tid = threadIdx.x, w = tid >> 6, lane = tid & 63;
  int lm = lane & 15, quad = lane >> 4;
  int wm = (w & 1) * 32, wn = (w >> 1) * 32;

  const short8* vAh = (const short8*)sAh;
  const short8* vAl = (const short8*)sAl;
  const short8* vWh = (const short8*)sWh;
  const short8* vWl = (const short8*)sWl;

  f32x4 acc[2][2] = {{{0.f,0.f,0.f,0.f},{0.f,0.f,0.f,0.f}},
                     {{0.f,0.f,0.f,0.f},{0.f,0.f,0.f,0.f}}};

  for (int k0 = 0; k0 < K; k0 += 64) {
    if (k0) __syncthreads();
    #pragma unroll
    for (int t = 0; t < 2; t++) {
      int f = t*256 + tid;
      int r = f >> 3, p = f & 7;
      int c = p ^ (r & 7);
      size_t goA = (size_t)(row0 + r)*K + k0 + c*8;
      size_t goW = (size_t)(col0 + r)*K + k0 + c*8;
      async_copy16(Ah + goA, &sAh[f*8]);
      async_copy16(Al + goA, &sAl[f*8]);
      async_copy16(Wh + goW, &sWh[f*8]);
      async_copy16(Wl + goW, &sWl[f*8]);
    }
    __syncthreads();

    #pragma unroll
    for (int ks = 0; ks < 2; ks++) {
      int kc = ks*4 + quad;
      short8 a_h[2], a_l[2], b_h[2], b_l[2];
      #pragma unroll
      for (int i = 0; i < 2; i++) {
        int m = wm + i*16 + lm;
        a_h[i] = vAh[m*8 + (kc ^ (m & 7))];
        a_l[i] = vAl[m*8 + (kc ^ (m & 7))];
      }
      #pragma unroll
      for (int j = 0; j < 2; j++) {
        int n = wn + j*16 + lm;
        b_h[j] = vWh[n*8 + (kc ^ (n & 7))];
        b_l[j] = vWl[n*8 + (kc ^ (n & 7))];
      }
      #pragma unroll
      for (int i = 0; i < 2; i++)
        #pragma unroll
        for (int j = 0; j < 2; j++) {
          acc[i][j] = __builtin_amdgcn_mfma_f32_16x16x32_bf16(a_h[i], b_h[j], acc[i][j], 0, 0, 0);
          acc[i][j] = __builtin_amdgcn_mfma_f32_16x16x32_bf16(a_h[i], b_l[j], acc[i][j], 0, 0, 0);
          acc[i][j] = __builtin_amdgcn_mfma_f32_16x16x32_bf16(a_l[i], b_h[j], acc[i][j], 0, 0, 0);
        }
    }
  }

  #pragma unroll
  for (int i = 0; i < 2; i++)
    #pragma unroll
    for (int j = 0; j < 2; j++) {
      int col = col0 + wn + j*16 + lm;
      float bj = bias[col];
      #pragma unroll
      for (int g = 0; g < 4; g++) {
        int row = row0 + wm + i*16 + quad*4 + g;
        float v = acc[i][j][g] + bj;
        v = v > 0.f ? v : 0.f;
        if (Cf) Cf[(size_t)row*N + col] = v;
        short hi, lo;
        if (Ch || Ph || Th) split_bf16(v, hi, lo);
        if (Ch) {
          Ch[(size_t)row*N + col] = hi;
          Cl[(size_t)row*N + col] = lo;
        }
        if (Ph) {
          size_t o = (size_t)row*packStride + (size_t)col*packMul;
          Ph[o] = hi; Pl[o] = lo;
        }
        if (Th) {  // transposed [B,64,V] (N==64)
          int bb = row >> 11, vv = row & (V_-1);
          size_t o = ((size_t)bb*64 + col)*V_ + vv;
          Th[o] = hi; Tl[o] = lo;
        }
      }
    }
}

// ---------------------------------------------------------------------------
// k_gemm_y1: y1 = relu(XK @ w1^T + b1); writes y1 fp32, ZK pack slot 0,
// and ZtA hi/lo transposed.  256 blocks (N=64).
// ---------------------------------------------------------------------------
__global__ __launch_bounds__(256) void k_gemm_y1(
    const short* __restrict__ XKh, const short* __restrict__ XKl,
    const short* __restrict__ w1h, const short* __restrict__ w1l,
    const float* __restrict__ b1, float* __restrict__ y1,
    short* __restrict__ ZKh, short* __restrict__ ZKl,
    short* __restrict__ Th, short* __restrict__ Tl) {
  __shared__ short sAh[64*64], sAl[64*64], sWh[64*64], sWl[64*64];
  gemm_tile(XKh, XKl, w1h, w1l, b1, 64, 64, blockIdx.x*64, 0,
            sAh, sAl, sWh, sWl,
            y1, nullptr, nullptr, ZKh, ZKl, 5, 320, Th, Tl);
}

// ---------------------------------------------------------------------------
// k_gemm_bf16: generic FC GEMM, 64x64 tiles.
// ---------------------------------------------------------------------------
__global__ __launch_bounds__(256) void k_gemm_bf16(
    const short* __restrict__ Ah, const short* __restrict__ Al,
    const short* __restrict__ Wh, const short* __restrict__ Wl,
    const float* __restrict__ bias, int N, int K,
    float* __restrict__ Cf, short* __restrict__ Ch, short* __restrict__ Cl) {
  __shared__ short sAh[64*64], sAl[64*64], sWh[64*64], sWl[64*64];
  int bm = blockIdx.x & 255;       // M_/64 = 256
  int bn = blockIdx.x >> 8;
  gemm_tile(Ah, Al, Wh, Wl, bias, N, K, bm*64, bn*64,
            sAh, sAl, sWh, sWl,
            Cf, Ch, Cl, nullptr, nullptr, 0, 0, nullptr, nullptr);
}

// ---------------------------------------------------------------------------
// ABLATION ROUND: byte-identical to the 536.4 us round-2 kernel, except each
// cheby2 launch is issued TWICE (idempotent: each step never reads an array
// it writes).  dur_us - 536.4 = cost of the 4-launch cheby2 family.
// ---------------------------------------------------------------------------
extern "C" void kernel_launch(void* const* d_in, const int* in_sizes, int n_in,
                              void* d_out, int out_size, void* d_ws, size_t ws_size,
                              hipStream_t stream) {
  const float* x   = (const float*)d_in[0];
  const float* L   = (const float*)d_in[1];
  const float* w1  = (const float*)d_in[2];
  const float* b1  = (const float*)d_in[3];
  const float* w2  = (const float*)d_in[4];
  const float* b2  = (const float*)d_in[5];
  const float* fw1 = (const float*)d_in[6];
  const float* fb1 = (const float*)d_in[7];
  const float* fw2 = (const float*)d_in[8];
  const float* fb2 = (const float*)d_in[9];
  float* out = (float*)d_out;

  float* p  = (float*)d_ws;
  float* xa = p;  p += (size_t)B_*V_*D_;
  float* xb = p;  p += (size_t)B_*V_*D_;
  float* xc = p;  p += (size_t)B_*V_*D_;
  float* y1 = p;  p += (size_t)M_*64;
  float* zb = p;  p += (size_t)M_*64;
  float* zc = p;  p += (size_t)M_*64;
  short* sp = (short*)p;
  short* ZKh = sp;  sp += (size_t)M_*320;
  short* ZKl = sp;  sp += (size_t)M_*320;
  short* y2h = sp;  sp += (size_t)M_*128;
  short* y2l = sp;  sp += (size_t)M_*128;
  short* h1h = sp;  sp += (size_t)M_*512;
  short* h1l = sp;  sp += (size_t)M_*512;
  short* ZtAh = sp; sp += (size_t)M_*64;
  short* ZtAl = sp; sp += (size_t)M_*64;
  short* ZtBh = sp; sp += (size_t)M_*64;
  short* ZtBl = sp; sp += (size_t)M_*64;
  short* w1h = sp;  sp += 64*64;
  short* w1l = sp;  sp += 64*64;
  short* w2h = sp;  sp += 128*320;
  short* w2l = sp;  sp += 128*320;
  short* fw1h = sp; sp += 512*128;
  short* fw1l = sp; sp += 512*128;
  short* fw2h = sp; sp += 256*512;
  short* fw2l = sp; sp += 256*512;
  // XK aliased into h1h region (disjoint lifetimes: XK dead before h1 written)
  short* XKh = h1h;
  short* XKl = h1h + (size_t)M_*64;

  // 1) prep
  k_prep<<<5040, 256, 0, stream>>>(x, w1, w2, fw1, fw2, xa,
                                   XKh, XKl, w1h, w1l, w2h, w2l,
                                   fw1h, fw1l, fw2h, fw2l);

  // 2) cheby1 chain
  k_cheby1<<<1024, 256, 0, stream>>>(L, xa, xa, xb, XKh, XKl, 1.f, 0.f, 1);
  k_cheby1<<<1024, 256, 0, stream>>>(L, xb, xa, xc, XKh, XKl, 2.f, 1.f, 2);
  k_cheby1<<<1024, 256, 0, stream>>>(L, xc, xb, xa, XKh, XKl, 2.f, 1.f, 3);
  k_cheby1<<<1024, 256, 0, stream>>>(L, xa, xc, xb, XKh, XKl, 2.f, 1.f, 4);
  k_cheby1<<<1024, 256, 0, stream>>>(L, xb, xa, xc, XKh, XKl, 2.f, 1.f, 5);

  // 3) y1-GEMM
  k_gemm_y1<<<256, 256, 0, stream>>>(XKh, XKl, w1h, w1l, b1,
                                     y1, ZKh, ZKl, ZtAh, ZtAl);

  // 4) cheby2 chain -- EACH STEP LAUNCHED TWICE (ablation probe, idempotent)
  k_cheby2_mfma<<<512, 256, 0, stream>>>(L, ZtAh, ZtAl, y1, zb, ZKh, ZKl,
                                         ZtBh, ZtBl, 1.f, 0.f, 1);
  k_cheby2_mfma<<<512, 256, 0, stream>>>(L, ZtAh, ZtAl, y1, zb, ZKh, ZKl,
                                         ZtBh, ZtBl, 1.f, 0.f, 1);
  k_cheby2_mfma<<<512, 256, 0, stream>>>(L, ZtBh, ZtBl, y1, zc, ZKh, ZKl,
                                         ZtAh, ZtAl, 2.f, 1.f, 2);
  k_cheby2_mfma<<<512, 256, 0, stream>>>(L, ZtBh, ZtBl, y1, zc, ZKh, ZKl,
                                         ZtAh, ZtAl, 2.f, 1.f, 2);
  k_cheby2_mfma<<<512, 256, 0, stream>>>(L, ZtAh, ZtAl, zb, y1, ZKh, ZKl,
                                         ZtBh, ZtBl, 2.f, 1.f, 3);
  k_cheby2_mfma<<<512, 256, 0, stream>>>(L, ZtAh, ZtAl, zb, y1, ZKh, ZKl,
                                         ZtBh, ZtBl, 2.f, 1.f, 3);
  k_cheby2_mfma<<<512, 256, 0, stream>>>(L, ZtBh, ZtBl, zc, zb, ZKh, ZKl,
                                         ZtAh, ZtAl, 2.f, 1.f, 4);
  k_cheby2_mfma<<<512, 256, 0, stream>>>(L, ZtBh, ZtBl, zc, zb, ZKh, ZKl,
                                         ZtAh, ZtAl, 2.f, 1.f, 4);

  // 5) FC chain
  k_gemm_bf16<<<512, 256, 0, stream>>>(ZKh, ZKl, w2h, w2l, b2, 128, 320,
                                       nullptr, y2h, y2l);
  k_gemm_bf16<<<2048, 256, 0, stream>>>(y2h, y2l, fw1h, fw1l, fb1, 512, 128,
                                        nullptr, h1h, h1l);
  k_gemm_bf16<<<1024, 256, 0, stream>>>(h1h, h1l, fw2h, fw2l, fb2, 256, 512,
                                        out, nullptr, nullptr);
}

// Round 7
// 531.556 us; speedup vs baseline: 2.9042x; 1.3139x over previous
//
#include <hip/hip_runtime.h>

#define B_ 8
#define V_ 2048
#define D_ 3
#define M_ (B_*V_)   // 16384 rows

typedef __attribute__((ext_vector_type(8))) short short8;
typedef __attribute__((ext_vector_type(4))) float f32x4;

__device__ inline void async_copy16(const void* g, void* lds) {
  __builtin_amdgcn_global_load_lds(
      (const __attribute__((address_space(1))) unsigned int*)g,
      (__attribute__((address_space(3))) unsigned int*)lds, 16, 0, 0);
}

__device__ inline void split_bf16(float v, short& hi, short& lo) {
  unsigned u  = __float_as_uint(v);
  unsigned hb = u & 0xFFFF0000u;
  float d = v - __uint_as_float(hb);
  hi = (short)(hb >> 16);
  lo = (short)(__float_as_uint(d) >> 16);
}

// ---------------------------------------------------------------------------
// k_prep: materialize XK (slot 0 from x-transpose, pads zero) + xa transpose
// + split all 4 weight matrices.  One launch, 5040 blocks x 256.
// ---------------------------------------------------------------------------
__global__ __launch_bounds__(256) void k_prep(
    const float* __restrict__ x,
    const float* __restrict__ w1, const float* __restrict__ w2,
    const float* __restrict__ fw1, const float* __restrict__ fw2,
    float* __restrict__ xa,
    short* __restrict__ XKh, short* __restrict__ XKl,
    short* __restrict__ w1h, short* __restrict__ w1l,
    short* __restrict__ w2h, short* __restrict__ w2l,
    short* __restrict__ fw1h, short* __restrict__ fw1l,
    short* __restrict__ fw2h, short* __restrict__ fw2l) {
  int i = blockIdx.x * 256 + threadIdx.x;
  short hi, lo;
  if (i < M_*64) {   // XK: row r = i>>6, slot s = i&63; slot = f*6+k, k=0 live
    int r = i >> 6, s = i & 63;
    float val = 0.f;
    if (s == 0 || s == 6 || s == 12) {
      int f = s / 6;
      int b = r >> 11, v = r & (V_-1);
      val = x[((size_t)b*D_ + f)*V_ + v];
      xa[(size_t)r*3 + f] = val;
    }
    split_bf16(val, hi, lo);
    XKh[i] = hi; XKl[i] = lo;
    return;
  }
  i -= M_*64;
  if (i < 4096) {          // w1: [64,18] -> [64,64] padded
    int n = i >> 6, k = i & 63;
    float v = (k < 18) ? w1[n*18 + k] : 0.f;
    split_bf16(v, hi, lo); w1h[i] = hi; w1l[i] = lo; return;
  }
  i -= 4096;
  if (i < 40960) { split_bf16(w2[i],  hi, lo); w2h[i]=hi;  w2l[i]=lo;  return; }
  i -= 40960;
  if (i < 65536) { split_bf16(fw1[i], hi, lo); fw1h[i]=hi; fw1l[i]=lo; return; }
  i -= 65536;
  if (i < 131072){ split_bf16(fw2[i], hi, lo); fw2h[i]=hi; fw2l[i]=lo; return; }
}

// ---------------------------------------------------------------------------
// k_cheby1: one recurrence step (3 features): xn = alpha*(L@xc) - beta*xp.
// 1024 blocks x 256: 16 rows/block, 4 rows/wave, batch pinned to XCD.
// (unchanged from the 536.4 us verified baseline)
// ---------------------------------------------------------------------------
__global__ __launch_bounds__(256) void k_cheby1(const float* __restrict__ L,
    const float* __restrict__ xc, const float* __restrict__ xp,
    float* __restrict__ xn, short* __restrict__ XKh, short* __restrict__ XKl,
    float alpha, float beta, int kidx) {
  __shared__ float sx[3][V_];  // 24 KB
  int b  = blockIdx.x & 7;          // batch -> XCD pin
  int r0 = (blockIdx.x >> 3) * 16;  // 128 tiles
  const float* xcb = xc + (size_t)b*V_*D_;
  for (int i = threadIdx.x; i < V_*D_; i += 256) {
    int u = i / 3, f = i - u*3;
    sx[f][u] = xcb[i];
  }
  __syncthreads();
  int w = threadIdx.x >> 6, lane = threadIdx.x & 63;
  const float4* X0 = (const float4*)sx[0];
  const float4* X1 = (const float4*)sx[1];
  const float4* X2 = (const float4*)sx[2];
  int rbase = r0 + w*4;
  const float4* Lr[4];
  #pragma unroll
  for (int rr = 0; rr < 4; rr++)
    Lr[rr] = (const float4*)(L + ((size_t)b*V_ + rbase + rr)*V_);

  float acc[4][3] = {{0.f,0.f,0.f},{0.f,0.f,0.f},{0.f,0.f,0.f},{0.f,0.f,0.f}};

  #pragma unroll 2
  for (int it = 0; it < 8; it++) {
    int u4 = it*64 + lane;
    float4 x0 = X0[u4], x1 = X1[u4], x2 = X2[u4];
    #pragma unroll
    for (int rr = 0; rr < 4; rr++) {
      float4 lv = Lr[rr][u4];
      acc[rr][0] = fmaf(lv.x,x0.x,fmaf(lv.y,x0.y,fmaf(lv.z,x0.z,fmaf(lv.w,x0.w,acc[rr][0]))));
      acc[rr][1] = fmaf(lv.x,x1.x,fmaf(lv.y,x1.y,fmaf(lv.z,x1.z,fmaf(lv.w,x1.w,acc[rr][1]))));
      acc[rr][2] = fmaf(lv.x,x2.x,fmaf(lv.y,x2.y,fmaf(lv.z,x2.z,fmaf(lv.w,x2.w,acc[rr][2]))));
    }
  }
  #pragma unroll
  for (int off = 32; off > 0; off >>= 1)
    #pragma unroll
    for (int rr = 0; rr < 4; rr++)
      #pragma unroll
      for (int f = 0; f < 3; f++)
        acc[rr][f] += __shfl_down(acc[rr][f], off);

  if (lane == 0) {
    size_t base = ((size_t)b*V_ + rbase)*3;   // 12 consecutive floats, 16B-aligned
    float v[12];
    #pragma unroll
    for (int rr = 0; rr < 4; rr++)
      #pragma unroll
      for (int f = 0; f < 3; f++)
        v[rr*3+f] = alpha*acc[rr][f];
    if (beta != 0.f) {
      const float4* xp4 = (const float4*)(xp + base);
      float4 p0 = xp4[0], p1 = xp4[1], p2 = xp4[2];
      v[0] -= beta*p0.x; v[1]  -= beta*p0.y; v[2]  -= beta*p0.z; v[3]  -= beta*p0.w;
      v[4] -= beta*p1.x; v[5]  -= beta*p1.y; v[6]  -= beta*p1.z; v[7]  -= beta*p1.w;
      v[8] -= beta*p2.x; v[9]  -= beta*p2.y; v[10] -= beta*p2.z; v[11] -= beta*p2.w;
    }
    float4* xn4 = (float4*)(xn + base);
    xn4[0] = make_float4(v[0], v[1], v[2],  v[3]);
    xn4[1] = make_float4(v[4], v[5], v[6],  v[7]);
    xn4[2] = make_float4(v[8], v[9], v[10], v[11]);
    #pragma unroll
    for (int rr = 0; rr < 4; rr++)
      #pragma unroll
      for (int f = 0; f < 3; f++) {
        short hi, lo; split_bf16(v[rr*3+f], hi, lo);
        size_t o = ((size_t)b*V_ + rbase + rr)*64 + f*6 + kidx;
        XKh[o] = hi; XKl[o] = lo;
      }
  }
}

// ---------------------------------------------------------------------------
// k_cheby2_mfma v4: Zn = alpha*(L @ z) - beta*Zp ; split-bf16 MFMA.
// 32-row x 64-col tiles -> 512 blocks, batch pinned to XCD.
// TRIPLE-buffered LDS (72 KB, 2 blk/CU) with COUNTED vmcnt — T3/T4-minimum:
//   prologue: stage(0), stage(1)           [12 loads in flight]
//   step s:   vmcnt(6)  -> only the newest stage may remain outstanding
//             s_barrier -> buf s%3 ready, buf (s-1)%3 free of readers
//             stage(s+2) into buf (s+2)%3 == (s-1)%3
//             compute buf s%3
// Each stage gets ~2 compute phases (~500-800 cyc) to land vs the old
// vmcnt(0)-per-step drain (~250-400 cyc slack).  Compute phase and epilogue
// are byte-identical to the verified kernel -> bit-identical results.
// ---------------------------------------------------------------------------
__global__ __launch_bounds__(256) void k_cheby2_mfma(const float* __restrict__ L,
    const short* __restrict__ Zth, const short* __restrict__ Ztl,
    const float* __restrict__ Zp,
    float* __restrict__ Zn, short* __restrict__ ZKh, short* __restrict__ ZKl,
    short* __restrict__ Znth, short* __restrict__ Zntl,
    float alpha, float beta, int kidx) {
  __shared__ float sA[3][32*64];    // L tile  [r][k], chunk-swizzled, 3x8 KB
  __shared__ short sBh[3][64*64];   // Zt hi   [n][k], chunk-swizzled, 3x8 KB
  __shared__ short sBl[3][64*64];   // Zt lo   [n][k], chunk-swizzled, 3x8 KB

  int b  = blockIdx.x & 7;              // batch -> XCD pin
  int r0 = (blockIdx.x >> 3) * 32;      // 64 row-tiles
  const float* Lb   = L   + (size_t)b*V_*V_;
  const short* Zthb = Zth + (size_t)b*64*V_;
  const short* Ztlb = Ztl + (size_t)b*64*V_;

  int tid  = threadIdx.x;
  int w    = tid >> 6;
  int lane = tid & 63;
  int lm   = lane & 15;
  int quad = lane >> 4;
  int cbase = w * 16;

  int f1  = tid + 256;
  int rA0 = tid >> 4, cA0 = (tid & 15) ^ (rA0 & 15);
  int rA1 = f1 >> 4,  cA1 = (f1 & 15) ^ (rA1 & 15);
  size_t gA0 = (size_t)(r0 + rA0)*V_ + cA0*4;
  size_t gA1 = (size_t)(r0 + rA1)*V_ + cA1*4;
  int nB0 = tid >> 3, cB0 = (tid & 7) ^ (nB0 & 7);
  int nB1 = f1 >> 3,  cB1 = (f1 & 7) ^ (nB1 & 7);
  size_t gB0 = (size_t)nB0*V_ + cB0*8;
  size_t gB1 = (size_t)nB1*V_ + cB1*8;

  auto stage = [&](int bb, int k0) {
    async_copy16(Lb   + gA0 + k0, &sA[bb][tid*4]);
    async_copy16(Lb   + gA1 + k0, &sA[bb][f1*4]);
    async_copy16(Zthb + gB0 + k0, &sBh[bb][tid*8]);
    async_copy16(Ztlb + gB0 + k0, &sBl[bb][tid*8]);
    async_copy16(Zthb + gB1 + k0, &sBh[bb][f1*8]);
    async_copy16(Ztlb + gB1 + k0, &sBl[bb][f1*8]);
  };

  f32x4 acc[2] = {{0.f,0.f,0.f,0.f},{0.f,0.f,0.f,0.f}};

  stage(0, 0);
  stage(1, 64);

  int cur = 0;
  for (int s = 0; s < V_/64; s++) {
    // drain everything older than the newest stage (6 loads). Last step:
    // only the current stage can be outstanding -> full drain.
    if (s < V_/64 - 1) asm volatile("s_waitcnt vmcnt(6)" ::: "memory");
    else               asm volatile("s_waitcnt vmcnt(0)" ::: "memory");
    __builtin_amdgcn_s_barrier();       // buf cur ready; buf (cur+2)%3 free
    __builtin_amdgcn_sched_barrier(0);
    if (s < V_/64 - 2) {
      int nb = cur + 2; if (nb >= 3) nb -= 3;
      stage(nb, (s+2)*64);
    }

    const f32x4*  sAv  = (const f32x4*)sA[cur];
    const short8* sBhv = (const short8*)sBh[cur];
    const short8* sBlv = (const short8*)sBl[cur];

    #pragma unroll
    for (int ks = 0; ks < 2; ks++) {
      int koff = ks * 32;
      short8 ah[2], al[2];
      #pragma unroll
      for (int t = 0; t < 2; t++) {
        int r = t*16 + lm;
        int ca = (koff >> 2) + 2*quad;
        f32x4 a0 = sAv[r*16 + (ca ^ (r & 15))];
        f32x4 a1 = sAv[r*16 + ((ca + 1) ^ (r & 15))];
        float av[8] = {a0.x, a0.y, a0.z, a0.w, a1.x, a1.y, a1.z, a1.w};
        #pragma unroll
        for (int j = 0; j < 8; j++) {
          short hi, lo; split_bf16(av[j], hi, lo);
          ah[t][j] = hi; al[t][j] = lo;
        }
      }
      int cb = (koff >> 3) + quad;
      int n = cbase + lm;
      short8 bh = sBhv[n*8 + (cb ^ (n & 7))];
      short8 bl = sBlv[n*8 + (cb ^ (n & 7))];
      __builtin_amdgcn_s_setprio(1);
      #pragma unroll
      for (int t = 0; t < 2; t++) {
        acc[t] = __builtin_amdgcn_mfma_f32_16x16x32_bf16(ah[t], bh, acc[t], 0, 0, 0);
        acc[t] = __builtin_amdgcn_mfma_f32_16x16x32_bf16(ah[t], bl, acc[t], 0, 0, 0);
        acc[t] = __builtin_amdgcn_mfma_f32_16x16x32_bf16(al[t], bh, acc[t], 0, 0, 0);
      }
      __builtin_amdgcn_s_setprio(0);
    }
    cur = (cur == 2) ? 0 : cur + 1;
  }

  int n = cbase + lm;
  #pragma unroll
  for (int t = 0; t < 2; t++) {
    #pragma unroll
    for (int i = 0; i < 4; i++) {
      int r = r0 + t*16 + quad*4 + i;
      size_t rowb = (size_t)b*V_ + r;
      float v = alpha * acc[t][i];
      if (beta != 0.f) v -= beta * Zp[rowb*64 + n];
      Zn[rowb*64 + n] = v;
      short hi, lo; split_bf16(v, hi, lo);
      size_t ok = rowb*320 + (size_t)n*5 + kidx;
      ZKh[ok] = hi; ZKl[ok] = lo;
      size_t o = ((size_t)b*64 + n)*V_ + r;
      Znth[o] = hi; Zntl[o] = lo;
    }
  }
}

// ---------------------------------------------------------------------------
// gemm_tile: one 64x64 output tile of C = relu(A[M,K] @ W[N,K]^T + bias).
// ---------------------------------------------------------------------------
__device__ __forceinline__ void gemm_tile(
    const short* __restrict__ Ah, const short* __restrict__ Al,
    const short* __restrict__ Wh, const short* __restrict__ Wl,
    const float* __restrict__ bias, int N, int K, int row0, int col0,
    short* sAh, short* sAl, short* sWh, short* sWl,
    float* __restrict__ Cf, short* __restrict__ Ch, short* __restrict__ Cl,
    short* __restrict__ Ph, short* __restrict__ Pl, int packMul, int packStride,
    short* __restrict__ Th, short* __restrict__ Tl) {
  int tid = threadIdx.x, w = tid >> 6, lane = tid & 63;
  int lm = lane & 15, quad = lane >> 4;
  int wm = (w & 1) * 32, wn = (w >> 1) * 32;

  const short8* vAh = (const short8*)sAh;
  const short8* vAl = (const short8*)sAl;
  const short8* vWh = (const short8*)sWh;
  const short8* vWl = (const short8*)sWl;

  f32x4 acc[2][2] = {{{0.f,0.f,0.f,0.f},{0.f,0.f,0.f,0.f}},
                     {{0.f,0.f,0.f,0.f},{0.f,0.f,0.f,0.f}}};

  for (int k0 = 0; k0 < K; k0 += 64) {
    if (k0) __syncthreads();
    #pragma unroll
    for (int t = 0; t < 2; t++) {
      int f = t*256 + tid;
      int r = f >> 3, p = f & 7;
      int c = p ^ (r & 7);
      size_t goA = (size_t)(row0 + r)*K + k0 + c*8;
      size_t goW = (size_t)(col0 + r)*K + k0 + c*8;
      async_copy16(Ah + goA, &sAh[f*8]);
      async_copy16(Al + goA, &sAl[f*8]);
      async_copy16(Wh + goW, &sWh[f*8]);
      async_copy16(Wl + goW, &sWl[f*8]);
    }
    __syncthreads();

    #pragma unroll
    for (int ks = 0; ks < 2; ks++) {
      int kc = ks*4 + quad;
      short8 a_h[2], a_l[2], b_h[2], b_l[2];
      #pragma unroll
      for (int i = 0; i < 2; i++) {
        int m = wm + i*16 + lm;
        a_h[i] = vAh[m*8 + (kc ^ (m & 7))];
        a_l[i] = vAl[m*8 + (kc ^ (m & 7))];
      }
      #pragma unroll
      for (int j = 0; j < 2; j++) {
        int n = wn + j*16 + lm;
        b_h[j] = vWh[n*8 + (kc ^ (n & 7))];
        b_l[j] = vWl[n*8 + (kc ^ (n & 7))];
      }
      #pragma unroll
      for (int i = 0; i < 2; i++)
        #pragma unroll
        for (int j = 0; j < 2; j++) {
          acc[i][j] = __builtin_amdgcn_mfma_f32_16x16x32_bf16(a_h[i], b_h[j], acc[i][j], 0, 0, 0);
          acc[i][j] = __builtin_amdgcn_mfma_f32_16x16x32_bf16(a_h[i], b_l[j], acc[i][j], 0, 0, 0);
          acc[i][j] = __builtin_amdgcn_mfma_f32_16x16x32_bf16(a_l[i], b_h[j], acc[i][j], 0, 0, 0);
        }
    }
  }

  #pragma unroll
  for (int i = 0; i < 2; i++)
    #pragma unroll
    for (int j = 0; j < 2; j++) {
      int col = col0 + wn + j*16 + lm;
      float bj = bias[col];
      #pragma unroll
      for (int g = 0; g < 4; g++) {
        int row = row0 + wm + i*16 + quad*4 + g;
        float v = acc[i][j][g] + bj;
        v = v > 0.f ? v : 0.f;
        if (Cf) Cf[(size_t)row*N + col] = v;
        short hi, lo;
        if (Ch || Ph || Th) split_bf16(v, hi, lo);
        if (Ch) {
          Ch[(size_t)row*N + col] = hi;
          Cl[(size_t)row*N + col] = lo;
        }
        if (Ph) {
          size_t o = (size_t)row*packStride + (size_t)col*packMul;
          Ph[o] = hi; Pl[o] = lo;
        }
        if (Th) {  // transposed [B,64,V] (N==64)
          int bb = row >> 11, vv = row & (V_-1);
          size_t o = ((size_t)bb*64 + col)*V_ + vv;
          Th[o] = hi; Tl[o] = lo;
        }
      }
    }
}

// ---------------------------------------------------------------------------
// k_gemm_y1: y1 = relu(XK @ w1^T + b1); writes y1 fp32, ZK pack slot 0,
// and ZtA hi/lo transposed.  256 blocks (N=64).
// ---------------------------------------------------------------------------
__global__ __launch_bounds__(256) void k_gemm_y1(
    const short* __restrict__ XKh, const short* __restrict__ XKl,
    const short* __restrict__ w1h, const short* __restrict__ w1l,
    const float* __restrict__ b1, float* __restrict__ y1,
    short* __restrict__ ZKh, short* __restrict__ ZKl,
    short* __restrict__ Th, short* __restrict__ Tl) {
  __shared__ short sAh[64*64], sAl[64*64], sWh[64*64], sWl[64*64];
  gemm_tile(XKh, XKl, w1h, w1l, b1, 64, 64, blockIdx.x*64, 0,
            sAh, sAl, sWh, sWl,
            y1, nullptr, nullptr, ZKh, ZKl, 5, 320, Th, Tl);
}

// ---------------------------------------------------------------------------
// k_gemm_bf16: generic FC GEMM, 64x64 tiles.
// ---------------------------------------------------------------------------
__global__ __launch_bounds__(256) void k_gemm_bf16(
    const short* __restrict__ Ah, const short* __restrict__ Al,
    const short* __restrict__ Wh, const short* __restrict__ Wl,
    const float* __restrict__ bias, int N, int K,
    float* __restrict__ Cf, short* __restrict__ Ch, short* __restrict__ Cl) {
  __shared__ short sAh[64*64], sAl[64*64], sWh[64*64], sWl[64*64];
  int bm = blockIdx.x & 255;       // M_/64 = 256
  int bn = blockIdx.x >> 8;
  gemm_tile(Ah, Al, Wh, Wl, bias, N, K, bm*64, bn*64,
            sAh, sAl, sWh, sWl,
            Cf, Ch, Cl, nullptr, nullptr, 0, 0, nullptr, nullptr);
}

// ---------------------------------------------------------------------------
extern "C" void kernel_launch(void* const* d_in, const int* in_sizes, int n_in,
                              void* d_out, int out_size, void* d_ws, size_t ws_size,
                              hipStream_t stream) {
  const float* x   = (const float*)d_in[0];
  const float* L   = (const float*)d_in[1];
  const float* w1  = (const float*)d_in[2];
  const float* b1  = (const float*)d_in[3];
  const float* w2  = (const float*)d_in[4];
  const float* b2  = (const float*)d_in[5];
  const float* fw1 = (const float*)d_in[6];
  const float* fb1 = (const float*)d_in[7];
  const float* fw2 = (const float*)d_in[8];
  const float* fb2 = (const float*)d_in[9];
  float* out = (float*)d_out;

  float* p  = (float*)d_ws;
  float* xa = p;  p += (size_t)B_*V_*D_;
  float* xb = p;  p += (size_t)B_*V_*D_;
  float* xc = p;  p += (size_t)B_*V_*D_;
  float* y1 = p;  p += (size_t)M_*64;
  float* zb = p;  p += (size_t)M_*64;
  float* zc = p;  p += (size_t)M_*64;
  short* sp = (short*)p;
  short* ZKh = sp;  sp += (size_t)M_*320;
  short* ZKl = sp;  sp += (size_t)M_*320;
  short* y2h = sp;  sp += (size_t)M_*128;
  short* y2l = sp;  sp += (size_t)M_*128;
  short* h1h = sp;  sp += (size_t)M_*512;
  short* h1l = sp;  sp += (size_t)M_*512;
  short* ZtAh = sp; sp += (size_t)M_*64;
  short* ZtAl = sp; sp += (size_t)M_*64;
  short* ZtBh = sp; sp += (size_t)M_*64;
  short* ZtBl = sp; sp += (size_t)M_*64;
  short* w1h = sp;  sp += 64*64;
  short* w1l = sp;  sp += 64*64;
  short* w2h = sp;  sp += 128*320;
  short* w2l = sp;  sp += 128*320;
  short* fw1h = sp; sp += 512*128;
  short* fw1l = sp; sp += 512*128;
  short* fw2h = sp; sp += 256*512;
  short* fw2l = sp; sp += 256*512;
  // XK aliased into h1h region (disjoint lifetimes: XK dead before h1 written)
  short* XKh = h1h;
  short* XKl = h1h + (size_t)M_*64;

  // 1) prep
  k_prep<<<5040, 256, 0, stream>>>(x, w1, w2, fw1, fw2, xa,
                                   XKh, XKl, w1h, w1l, w2h, w2l,
                                   fw1h, fw1l, fw2h, fw2l);

  // 2) cheby1 chain
  k_cheby1<<<1024, 256, 0, stream>>>(L, xa, xa, xb, XKh, XKl, 1.f, 0.f, 1);
  k_cheby1<<<1024, 256, 0, stream>>>(L, xb, xa, xc, XKh, XKl, 2.f, 1.f, 2);
  k_cheby1<<<1024, 256, 0, stream>>>(L, xc, xb, xa, XKh, XKl, 2.f, 1.f, 3);
  k_cheby1<<<1024, 256, 0, stream>>>(L, xa, xc, xb, XKh, XKl, 2.f, 1.f, 4);
  k_cheby1<<<1024, 256, 0, stream>>>(L, xb, xa, xc, XKh, XKl, 2.f, 1.f, 5);

  // 3) y1-GEMM
  k_gemm_y1<<<256, 256, 0, stream>>>(XKh, XKl, w1h, w1l, b1,
                                     y1, ZKh, ZKl, ZtAh, ZtAl);

  // 4) cheby2 chain (pipelined v4)
  k_cheby2_mfma<<<512, 256, 0, stream>>>(L, ZtAh, ZtAl, y1, zb, ZKh, ZKl,
                                         ZtBh, ZtBl, 1.f, 0.f, 1);
  k_cheby2_mfma<<<512, 256, 0, stream>>>(L, ZtBh, ZtBl, y1, zc, ZKh, ZKl,
                                         ZtAh, ZtAl, 2.f, 1.f, 2);
  k_cheby2_mfma<<<512, 256, 0, stream>>>(L, ZtAh, ZtAl, zb, y1, ZKh, ZKl,
                                         ZtBh, ZtBl, 2.f, 1.f, 3);
  k_cheby2_mfma<<<512, 256, 0, stream>>>(L, ZtBh, ZtBl, zc, zb, ZKh, ZKl,
                                         ZtAh, ZtAl, 2.f, 1.f, 4);

  // 5) FC chain
  k_gemm_bf16<<<512, 256, 0, stream>>>(ZKh, ZKl, w2h, w2l, b2, 128, 320,
                                       nullptr, y2h, y2l);
  k_gemm_bf16<<<2048, 256, 0, stream>>>(y2h, y2l, fw1h, fw1l, fb1, 512, 128,
                                        nullptr, h1h, h1l);
  k_gemm_bf16<<<1024, 256, 0, stream>>>(h1h, h1l, fw2h, fw2l, fb2, 256, 512,
                                        out, nullptr, nullptr);
}